// Round 7
// baseline (408.379 us; speedup 1.0000x reference)
//
#include <hip/hip_runtime.h>
#include <stdint.h>

// Problem constants
#define N_ENTS  100000
#define N_RELS  16
#define DIM     128
#define NB      4
#define TILE_U  10240           // ushorts per WtT n-tile: 80*16*8
#define NEDGE   640000
#define BATCH   1024
#define NNEG    64
#define BN_EPS  1e-5f
#define BCAP    64              // bucket capacity per node
#define SENTR   0x01000000u     // sentinel record: rel=16 (zero coeff), src=0
#define NPB     32              // nodes per fused block
#define NBLK2   3125            // N_ENTS/NPB exact
#define CONVX_BLKS 6250
#define CONVP_BLKS 652          // ceil(P_TOTAL/256)

// converted-parameter buffer layout (ushort offsets)
#define P_REL    0        // [16][128]
#define P_BASES  2048     // [2][4][128][128]
#define P_COEFF  133120   // [2][16][4]
#define P_WSL    133248   // [2][128][128]
#define P_BSL    166016   // [2][128]
#define P_GAMMA  166272   // [2][128]
#define P_BETA   166528   // [2][128]
#define P_TOTAL  166784

typedef unsigned int uint;
typedef short short8 __attribute__((ext_vector_type(8)));
typedef float f4 __attribute__((ext_vector_type(4)));

__device__ __forceinline__ float bf2f(unsigned short u) {
    return __uint_as_float(((unsigned int)u) << 16);
}
__device__ __forceinline__ float bflo(unsigned int u) { return __uint_as_float(u << 16); }
__device__ __forceinline__ float bfhi(unsigned int u) { return __uint_as_float(u & 0xffff0000u); }
__device__ __forceinline__ unsigned short f2bf(float f) {
    unsigned int x = __float_as_uint(f);
    x += 0x7fffu + ((x >> 16) & 1u);
    return (unsigned short)(x >> 16);
}
__device__ __forceinline__ unsigned int pack2(float a, float b) {
    return (unsigned int)f2bf(a) | ((unsigned int)f2bf(b) << 16);
}

// ---------------- dtype detection (fp32 vs bf16 storage) ----------------
__device__ __forceinline__ int bf16_like(unsigned int h) {
    unsigned int m = h & 0x7FFFu;
    return (m == 0u) || (m >= 0x2D00u && m < 0x4400u);
}
__global__ __launch_bounds__(256) void k_detect(const unsigned int* __restrict__ ent,
                                                int* __restrict__ flag) {
    __shared__ int cnt[256];
    unsigned int u = ent[threadIdx.x];
    cnt[threadIdx.x] = bf16_like(u & 0xFFFFu) & bf16_like(u >> 16);
    __syncthreads();
    for (int s = 128; s > 0; s >>= 1) {
        if (threadIdx.x < s) cnt[threadIdx.x] += cnt[threadIdx.x + s];
        __syncthreads();
    }
    if (threadIdx.x == 0) flag[0] = (cnt[0] >= 140) ? 1 : 0;
}

// ---------------- merged convert: x (fp32 path only) + params ----------------
__device__ __forceinline__ unsigned short cvt1(const void* src, int i, int isbf) {
    return isbf ? ((const unsigned short*)src)[i] : f2bf(((const float*)src)[i]);
}
__global__ __launch_bounds__(256) void k_conv(
    const void* __restrict__ src, unsigned short* __restrict__ xrow,
    const void* __restrict__ rtab, const void* __restrict__ bases,
    const void* __restrict__ coeffs, const void* __restrict__ wsl,
    const void* __restrict__ bsl, const void* __restrict__ gamma,
    const void* __restrict__ beta,
    unsigned short* __restrict__ par, const int* __restrict__ flag)
{
    const int isbf = flag[0];
    if (blockIdx.x < CONVX_BLKS) {
        if (isbf) return;                        // bf16 input: ent used directly, no copy
        const int kc = threadIdx.x >> 4, r = threadIdx.x & 15;
        const int n = blockIdx.x * 16 + r;
        const size_t e0 = (size_t)n * DIM + kc * 8;
        const float4 f0 = *(const float4*)((const float*)src + e0);
        const float4 f1 = *(const float4*)((const float*)src + e0 + 4);
        uint4 w;
        w.x = pack2(f0.x, f0.y); w.y = pack2(f0.z, f0.w);
        w.z = pack2(f1.x, f1.y); w.w = pack2(f1.z, f1.w);
        *(uint4*)(xrow + e0) = w;
        return;
    }
    const int i = (blockIdx.x - CONVX_BLKS) * 256 + threadIdx.x;
    if (i >= P_TOTAL) return;
    unsigned short v;
    if      (i < P_BASES)  v = cvt1(rtab,   i - P_REL,    isbf);
    else if (i < P_COEFF)  v = cvt1(bases,  i - P_BASES,  isbf);
    else if (i < P_WSL)    v = cvt1(coeffs, i - P_COEFF,  isbf);
    else if (i < P_BSL)    v = cvt1(wsl,    i - P_WSL,    isbf);
    else if (i < P_GAMMA)  v = cvt1(bsl,    i - P_BSL,    isbf);
    else if (i < P_BETA)   v = cvt1(gamma,  i - P_GAMMA,  isbf);
    else                   v = cvt1(beta,   i - P_BETA,   isbf);
    par[i] = v;
}

// ---------------- one-kernel bucket CSR: cnt + bucket[n][64] ----------------
__global__ __launch_bounds__(256) void k_fillB(const int* __restrict__ src, const int* __restrict__ dst,
                                               const int* __restrict__ et, int* __restrict__ cnt,
                                               uint* __restrict__ bucket) {
    const int e = blockIdx.x * 256 + threadIdx.x;   // grid exact: NEDGE/256
    const int d = dst[e];
    const int p = atomicAdd(&cnt[d], 1);
    if (p < BCAP) bucket[(size_t)d * BCAP + p] = (uint)src[e] | ((uint)et[e] << 20);
}

// ---------------- WtT tiled (blocks 0..79) + fp32 coeff table (block 80) ----------------
// WtT: [l][jt 8][kc 80][r 16][8]. cf32: [2][17][4], rel=16 zero (tail mask) -> branch-free FMA
__global__ __launch_bounds__(256) void k_transw2(const unsigned short* __restrict__ par,
                                                 unsigned short* __restrict__ WtT,
                                                 float* __restrict__ cf32) {
    if (blockIdx.x == 80) {
        const int i = threadIdx.x;
        if (i < 2 * 17 * 4) {
            const int l = i / 68, rem = i - l * 68, r = rem >> 2, b = rem & 3;
            cf32[i] = (r < N_RELS) ? bf2f(par[P_COEFF + l * N_RELS * NB + r * NB + b]) : 0.f;
        }
        return;
    }
    const int i = blockIdx.x * 256 + threadIdx.x;   // blocks 0..79: 20480 items
    const int l = i / 10240;
    const int rem = i - l * 10240;
    const int jt2 = rem / 1280;
    const int rem2 = rem - jt2 * 1280;
    const int kc = rem2 >> 4, r = rem2 & 15;
    const int n = jt2 * 16 + r;
    unsigned short v[8];
#pragma unroll
    for (int e = 0; e < 8; ++e) {
        const int k = kc * 8 + e;
        v[e] = (k < DIM)
            ? par[P_WSL + l * DIM * DIM + k * DIM + n]
            : par[P_BASES + l * NB * DIM * DIM + (k - DIM) * DIM + n];
    }
    *(uint4*)(WtT + (size_t)l * 81920 + (size_t)jt2 * TILE_U + (size_t)kc * 128 + r * 8) = *(uint4*)v;
}

// ---------------- FUSED (BN of prev layer) + aggregate + GEMM + epilogue ----------------
// 256 thr (4 waves), NPB=32. LDS A-tile [32][640] bf16, 40960B, swizzle byte^=(row&7)<<4.
// LAY template: layer-0 inner loop has NO BN ops (compile-time).
// Phase 2: TWO concurrent gather chains (4 nodes) per iteration — 32 loads in flight
// before any FMA wait, chain A's FMA hides chain B's latency.
// No min-waves bound: (256,8) spilled ~550MB (r3); allocator picks VGPR naturally.
template<int LAY>
__global__ __launch_bounds__(256) void k_fused(
    const uint* __restrict__ bucket, const int* __restrict__ cnt,
    const float* __restrict__ cf, const unsigned short* __restrict__ xin,
    const void* __restrict__ ent, const int* __restrict__ flag,
    const float* __restrict__ stp, const unsigned short* __restrict__ gprev,
    const unsigned short* __restrict__ bprev,
    const unsigned short* __restrict__ wtT, const unsigned short* __restrict__ bsl,
    unsigned short* __restrict__ out, float* __restrict__ pstats)
{
    __shared__ unsigned short Ash[NPB * 640];      // 40960 B
    const int tid = threadIdx.x;
    const int wave = tid >> 6, lane = tid & 63;
    const int n0 = blockIdx.x * NPB;
    const float inv_n = 1.0f / (float)N_ENTS;

    const unsigned short* __restrict__ xs =
        (LAY == 0 && flag[0]) ? (const unsigned short*)ent : xin;

    // per-lane BN coeffs for gather columns {2*lane, 2*lane+1} (layer 1 only)
    float gnA = 1.f, ofA = 0.f, gnB = 1.f, ofB = 0.f;
    if (LAY) {
        const int f0 = lane * 2, f1 = f0 + 1;
        const float mu0 = stp[f0] * inv_n, mu1 = stp[f1] * inv_n;
        const float va0 = stp[DIM + f0] * inv_n - mu0 * mu0;
        const float va1 = stp[DIM + f1] * inv_n - mu1 * mu1;
        gnA = bf2f(gprev[f0]) * rsqrtf(va0 + BN_EPS); ofA = bf2f(bprev[f0]) - mu0 * gnA;
        gnB = bf2f(gprev[f1]) * rsqrtf(va1 + BN_EPS); ofB = bf2f(bprev[f1]) - mu1 * gnB;
    }

    // ---- phase 1: stage self rows into LDS (k 0..127 = 256B/row), swizzled, BN-applied
    {
        const int r = tid >> 3, c = tid & 7;       // 32 rows; chunks c and c+8 (16B each)
        const size_t e0 = (size_t)(n0 + r) * DIM + c * 8;
        uint4 v0 = *(const uint4*)(xs + e0);
        uint4 v1 = *(const uint4*)(xs + e0 + 64);
        if (LAY) {
            uint vv[8] = {v0.x, v0.y, v0.z, v0.w, v1.x, v1.y, v1.z, v1.w};
#pragma unroll
            for (int p = 0; p < 8; ++p) {
                const int f0 = c * 8 + (p >> 2) * 64 + (p & 3) * 2;
                const float mu0 = stp[f0] * inv_n, mu1 = stp[f0 + 1] * inv_n;
                const float va0 = stp[DIM + f0] * inv_n - mu0 * mu0;
                const float va1 = stp[DIM + f0 + 1] * inv_n - mu1 * mu1;
                const float g0 = bf2f(gprev[f0]) * rsqrtf(va0 + BN_EPS);
                const float g1 = bf2f(gprev[f0 + 1]) * rsqrtf(va1 + BN_EPS);
                const float o0 = bf2f(bprev[f0]) - mu0 * g0;
                const float o1 = bf2f(bprev[f0 + 1]) - mu1 * g1;
                const float w0 = fmaxf(fmaf(bflo(vv[p]), g0, o0), 0.f);
                const float w1 = fmaxf(fmaf(bfhi(vv[p]), g1, o1), 0.f);
                vv[p] = pack2(w0, w1);
            }
            v0.x = vv[0]; v0.y = vv[1]; v0.z = vv[2]; v0.w = vv[3];
            v1.x = vv[4]; v1.y = vv[5]; v1.z = vv[6]; v1.w = vv[7];
        }
        const int byte0 = (r * 1280 + c * 16) ^ ((r & 7) << 4);
        *(uint4*)((char*)Ash + byte0) = v0;
        *(uint4*)((char*)Ash + byte0 + 128) = v1;   // +128: bit7 only, outside XOR bits 4-6
    }

    // ---- phase 2: gather-aggregate, two concurrent chains (A: nodes +0,+1; B: +2,+3)
    const uint* __restrict__ x32 = (const uint*)xs;
    const int mybase = n0 + wave * 8;
    for (int pp = 0; pp < 2; ++pp) {
        const int naA = mybase + pp * 4;
        const int naB = naA + 2;
        int cA0 = cnt[naA];     if (cA0 > BCAP) cA0 = BCAP;
        int cA1 = cnt[naA + 1]; if (cA1 > BCAP) cA1 = BCAP;
        int cB0 = cnt[naB];     if (cB0 > BCAP) cB0 = BCAP;
        int cB1 = cnt[naB + 1]; if (cB1 > BCAP) cB1 = BCAP;
        const int qm0 = ((cA0 > cA1 ? cA0 : cA1) + 7) >> 3;
        const int qm1 = ((cB0 > cB1 ? cB0 : cB1) + 7) >> 3;
        const int qm = qm0 > qm1 ? qm0 : qm1;
        float accLo[4][NB] = {{0.f,0.f,0.f,0.f},{0.f,0.f,0.f,0.f},
                              {0.f,0.f,0.f,0.f},{0.f,0.f,0.f,0.f}};
        float accHi[4][NB] = {{0.f,0.f,0.f,0.f},{0.f,0.f,0.f,0.f},
                              {0.f,0.f,0.f,0.f},{0.f,0.f,0.f,0.f}};
        const uint4* __restrict__ bkA = (const uint4*)(bucket + (size_t)naA * BCAP);
        const uint4* __restrict__ bkB = (const uint4*)(bucket + (size_t)naB * BCAP);
        for (int j = 0; j < qm; ++j) {
            const int b8 = j * 8;
            uint rec[4][8];
            uint xw[4][8];
            const int cns[4] = {cA0, cA1, cB0, cB1};
            // issue ALL bucket loads + gathers for both chains before any FMA wait
#pragma unroll
            for (int g = 0; g < 4; ++g) {
                const int cn = cns[g];
                if (b8 < cn) {
                    const uint4* bk = (g < 2) ? bkA : bkB;
                    const int h = g & 1;
                    const uint4 r0 = bk[h * 16 + j * 2];
                    const uint4 r1 = bk[h * 16 + j * 2 + 1];
                    rec[g][0] = r0.x; rec[g][1] = r0.y; rec[g][2] = r0.z; rec[g][3] = r0.w;
                    rec[g][4] = r1.x; rec[g][5] = r1.y; rec[g][6] = r1.z; rec[g][7] = r1.w;
#pragma unroll
                    for (int s = 0; s < 8; ++s) {
                        uint rr = (uint)__builtin_amdgcn_readfirstlane((int)rec[g][s]);
                        if (b8 + s >= cn) rr = SENTR;        // uniform tail mask
                        rec[g][s] = rr;                      // uniform -> SGPR base
                        xw[g][s] = x32[(size_t)(rr & 0xFFFFFu) * 64 + lane];
                    }
                }
            }
#pragma unroll
            for (int g = 0; g < 4; ++g) {
                const int cn = cns[g];
                if (b8 < cn) {
#pragma unroll
                    for (int s = 0; s < 8; ++s) {
                        const int rel = (int)(rec[g][s] >> 20);   // uniform; 16 -> zero coeffs
                        const float4 cc = *(const float4*)(cf + rel * 4);  // s_load_dwordx4
                        float xl, xh;
                        if (LAY) {
                            xl = fmaxf(fmaf(bflo(xw[g][s]), gnA, ofA), 0.f);
                            xh = fmaxf(fmaf(bfhi(xw[g][s]), gnB, ofB), 0.f);
                        } else {
                            xl = bflo(xw[g][s]);
                            xh = bfhi(xw[g][s]);
                        }
                        accLo[g][0] = fmaf(cc.x, xl, accLo[g][0]);
                        accHi[g][0] = fmaf(cc.x, xh, accHi[g][0]);
                        accLo[g][1] = fmaf(cc.y, xl, accLo[g][1]);
                        accHi[g][1] = fmaf(cc.y, xh, accHi[g][1]);
                        accLo[g][2] = fmaf(cc.z, xl, accLo[g][2]);
                        accHi[g][2] = fmaf(cc.z, xh, accHi[g][2]);
                        accLo[g][3] = fmaf(cc.w, xl, accLo[g][3]);
                        accHi[g][3] = fmaf(cc.w, xh, accHi[g][3]);
                    }
                }
            }
        }
#pragma unroll
        for (int g = 0; g < 4; ++g) {
            const int ra = wave * 8 + pp * 4 + g;
            const int swz = (ra & 7) << 4;
#pragma unroll
            for (int b = 0; b < NB; ++b) {
                // A[ra][128 + b*128 + 2*lane .. +1]  (bank-conflict-free: lane*4 stride)
                const int byte = (ra * 1280 + 256 + b * 256 + lane * 4) ^ swz;
                *(uint*)((char*)Ash + byte) = pack2(accLo[g][b], accHi[g][b]);
            }
        }
    }

    // ---- phase 3: MFMA. wave w: m-tiles {0,1} x n-tiles {2w,2w+1}, K=640 (20 steps)
    const int quad = lane >> 4, l16 = lane & 15;
    f4 acc[2][2];
#pragma unroll
    for (int i = 0; i < 2; ++i)
#pragma unroll
        for (int j = 0; j < 2; ++j)
#pragma unroll
            for (int r = 0; r < 4; ++r) acc[i][j][r] = 0.f;

    const unsigned short* __restrict__ pB0 = wtT + (size_t)(2 * wave) * TILE_U + quad * 128 + l16 * 8;
    const unsigned short* __restrict__ pB1 = pB0 + TILE_U;
    const char* Ab = (const char*)Ash;
    const int swz = (l16 & 7) << 4;
    // even/odd ks bases: XOR touches bits 4-6 and ks*64 carries bit 6 -> two bases
    const int b0e = (l16 * 1280 + quad * 16) ^ swz;
    const int b0o = (l16 * 1280 + 64 + quad * 16) ^ swz;
    const int b1e = ((l16 + 16) * 1280 + quad * 16) ^ swz;
    const int b1o = ((l16 + 16) * 1280 + 64 + quad * 16) ^ swz;

    short8 xa0, xa1, xb0, xb1, ya0, ya1, yb0, yb1;
#define FLDA(P, s) \
    P##a0 = *(const short8*)(Ab + (((s) & 1) ? b0o : b0e) + ((s) >> 1) * 128); \
    P##a1 = *(const short8*)(Ab + (((s) & 1) ? b1o : b1e) + ((s) >> 1) * 128);
#define FLDB(P, s) \
    P##b0 = *(const short8*)(pB0 + (s) * 512); \
    P##b1 = *(const short8*)(pB1 + (s) * 512);
#define FLD(P, s) FLDA(P, s) FLDB(P, s)
#define FMM(P) \
    acc[0][0] = __builtin_amdgcn_mfma_f32_16x16x32_bf16(P##a0, P##b0, acc[0][0], 0, 0, 0); \
    acc[0][1] = __builtin_amdgcn_mfma_f32_16x16x32_bf16(P##a0, P##b1, acc[0][1], 0, 0, 0); \
    acc[1][0] = __builtin_amdgcn_mfma_f32_16x16x32_bf16(P##a1, P##b0, acc[1][0], 0, 0, 0); \
    acc[1][1] = __builtin_amdgcn_mfma_f32_16x16x32_bf16(P##a1, P##b1, acc[1][1], 0, 0, 0);

    // B loads are global (no LDS dependency): issue before the barrier
    FLDB(x, 0) FLDB(y, 1)
    __syncthreads();
    FLDA(x, 0) FLDA(y, 1)
    FMM(x) FLD(x, 2)
    FMM(y) FLD(y, 3)
    FMM(x) FLD(x, 4)
    FMM(y) FLD(y, 5)
    FMM(x) FLD(x, 6)
    FMM(y) FLD(y, 7)
    FMM(x) FLD(x, 8)
    FMM(y) FLD(y, 9)
    FMM(x) FLD(x, 10)
    FMM(y) FLD(y, 11)
    FMM(x) FLD(x, 12)
    FMM(y) FLD(y, 13)
    FMM(x) FLD(x, 14)
    FMM(y) FLD(y, 15)
    FMM(x) FLD(x, 16)
    FMM(y) FLD(y, 17)
    FMM(x) FLD(x, 18)
    FMM(y) FLD(y, 19)
    FMM(x)
    FMM(y)
#undef FLDA
#undef FLDB
#undef FLD
#undef FMM

    // ---- epilogue: o = (acc + bias)/deg, bf16 store, per-block BN partial stats
    float ssum[2] = {0.f, 0.f}, sssq[2] = {0.f, 0.f};
#pragma unroll
    for (int m = 0; m < 2; ++m) {
#pragma unroll
        for (int r = 0; r < 4; ++r) {
            const int row = n0 + m * 16 + quad * 4 + r;    // always < N_ENTS (3125*32 exact)
            const float rdeg = 1.0f / fmaxf((float)cnt[row], 1.0f);
#pragma unroll
            for (int n = 0; n < 2; ++n) {
                const int col = (2 * wave + n) * 16 + l16;
                const float o = (acc[m][n][r] + bf2f(bsl[col])) * rdeg;
                out[(size_t)row * DIM + col] = f2bf(o);
                ssum[n] += o;
                sssq[n] += o * o;
            }
        }
    }
#pragma unroll
    for (int n = 0; n < 2; ++n) {
        float s = ssum[n], q2 = sssq[n];
        s += __shfl_xor(s, 16, 64);  s += __shfl_xor(s, 32, 64);
        q2 += __shfl_xor(q2, 16, 64); q2 += __shfl_xor(q2, 32, 64);
        if (quad == 0) {
            const int col = (2 * wave + n) * 16 + l16;
            pstats[(size_t)blockIdx.x * 256 + col] = s;
            pstats[(size_t)blockIdx.x * 256 + 128 + col] = q2;
        }
    }
}

// ---------------- reduce per-block stats -> st[256] ----------------
__global__ __launch_bounds__(256) void k_stats(const float* __restrict__ pstats,
                                               float* __restrict__ st) {
    const int o = threadIdx.x;
    const int b0 = blockIdx.x * 25;                // grid 125: 125*25 = 3125 exact
    float s = 0.f;
    for (int b = b0; b < b0 + 25; ++b)
        s += pstats[(size_t)b * 256 + o];
    atomicAdd(&st[o], s);
}

// ---------------- fused scoring: BN1+ReLU applied to gathered embeddings ----------------
__global__ __launch_bounds__(256) void k_score(
    const int* __restrict__ head, const int* __restrict__ rel,
    const int* __restrict__ tail, const int* __restrict__ negi,
    const unsigned short* __restrict__ emb, const unsigned short* __restrict__ rtab,
    const float* __restrict__ st1, const unsigned short* __restrict__ gm1,
    const unsigned short* __restrict__ bt1,
    void* __restrict__ outp, const int* __restrict__ flag)
{
    const int wave = threadIdx.x >> 6, lane = threadIdx.x & 63;
    const int w = blockIdx.x * 4 + wave;   // grid exact: (BATCH + BATCH*NNEG)/4
    const float inv_n = 1.0f / (float)N_ENTS;
    const int f0 = lane * 2, f1 = f0 + 1;
    const float mu0 = st1[f0] * inv_n, mu1 = st1[f1] * inv_n;
    const float va0 = st1[DIM + f0] * inv_n - mu0 * mu0;
    const float va1 = st1[DIM + f1] * inv_n - mu1 * mu1;
    const float g0 = bf2f(gm1[f0]) * rsqrtf(va0 + BN_EPS);
    const float g1 = bf2f(gm1[f1]) * rsqrtf(va1 + BN_EPS);
    const float o0 = bf2f(bt1[f0]) - mu0 * g0;
    const float o1 = bf2f(bt1[f1]) - mu1 * g1;

    int i, t;
    if (w < BATCH) { i = w; t = tail[w]; }
    else { const int w2 = w - BATCH; i = w2 >> 6; t = negi[w2]; }
    const uint hv = ((const uint*)emb)[(size_t)head[i] * 64 + lane];
    const uint rv = ((const uint*)rtab)[(size_t)rel[i] * 64 + lane];
    const uint tv = ((const uint*)emb)[(size_t)t * 64 + lane];
    const float h0 = fmaxf(fmaf(bflo(hv), g0, o0), 0.f);
    const float h1 = fmaxf(fmaf(bfhi(hv), g1, o1), 0.f);
    const float t0 = fmaxf(fmaf(bflo(tv), g0, o0), 0.f);
    const float t1 = fmaxf(fmaf(bfhi(tv), g1, o1), 0.f);
    const float d0 = (h0 + bflo(rv)) - t0;
    const float d1 = (h1 + bfhi(rv)) - t1;
    float s = d0 * d0 + d1 * d1;
#pragma unroll
    for (int m = 32; m >= 1; m >>= 1) s += __shfl_xor(s, m, 64);
    if (lane == 0) {
        const float v = -sqrtf(s);
        if (flag[0]) ((unsigned short*)outp)[w] = f2bf(v);
        else         ((float*)outp)[w] = v;
    }
}

extern "C" void kernel_launch(void* const* d_in, const int* in_sizes, int n_in,
                              void* d_out, int out_size, void* d_ws, size_t ws_size,
                              hipStream_t stream)
{
    const int* head = (const int*)d_in[0];
    const int* rel  = (const int*)d_in[1];
    const int* tail = (const int*)d_in[2];
    const int* negi = (const int*)d_in[3];
    const int* eidx = (const int*)d_in[4];
    const int* etyp = (const int*)d_in[5];
    const void* ent_tab = d_in[6];
    const void* rtab_in = d_in[7];
    const void* bases_in = d_in[8];
    const void* coeffs_in = d_in[9];
    const void* wsl_in = d_in[10];
    const void* bsl_in = d_in[11];
    const void* gamma_in = d_in[12];
    const void* beta_in = d_in[13];

    char* ws = (char*)d_ws;
    size_t off = 0;
    auto alloc = [&](size_t bytes) -> char* {
        char* p = ws + off;
        off += (bytes + 511) & ~(size_t)511;
        return p;
    };
    int* flag            = (int*)alloc(4);
    int* cnt             = (int*)alloc((size_t)N_ENTS * 4);
    uint* bucket         = (uint*)alloc((size_t)N_ENTS * BCAP * 4);             // 25.6 MB
    unsigned short* xrow = (unsigned short*)alloc((size_t)N_ENTS * DIM * 2);    // fp32-input path only
    unsigned short* outA = (unsigned short*)alloc((size_t)N_ENTS * DIM * 2);    // layer-0 raw out
    unsigned short* outB = (unsigned short*)alloc((size_t)N_ENTS * DIM * 2);    // layer-1 raw out
    unsigned short* par  = (unsigned short*)alloc((size_t)P_TOTAL * 2);
    unsigned short* WtT  = (unsigned short*)alloc((size_t)2 * 81920 * 2);
    float* cf32          = (float*)alloc((size_t)2 * 17 * 4 * 4);
    float* pstats        = (float*)alloc((size_t)NBLK2 * 256 * 4);              // 3.2 MB
    float* stats         = (float*)alloc(2 * 2 * DIM * 4);
    (void)ws_size; (void)in_sizes; (void)n_in; (void)out_size;

    const int* esrc = eidx;
    const int* edst = eidx + NEDGE;

    k_detect<<<1, 256, 0, stream>>>((const unsigned int*)ent_tab, flag);

    k_conv<<<CONVX_BLKS + CONVP_BLKS, 256, 0, stream>>>(
        ent_tab, xrow, rtab_in, bases_in, coeffs_in, wsl_in, bsl_in, gamma_in, beta_in,
        par, flag);
    k_transw2<<<81, 256, 0, stream>>>(par, WtT, cf32);

    hipMemsetAsync(cnt, 0, (size_t)N_ENTS * 4, stream);
    hipMemsetAsync(stats, 0, 2 * 2 * DIM * 4, stream);

    k_fillB<<<NEDGE / 256, 256, 0, stream>>>(esrc, edst, etyp, cnt, bucket);

    // layer 0 (no BN on input)
    k_fused<0><<<NBLK2, 256, 0, stream>>>(
        bucket, cnt, cf32, xrow, ent_tab, flag,
        stats, par + P_GAMMA, par + P_BETA,          // unused at LAY=0
        WtT, par + P_BSL, outA, pstats);
    k_stats<<<125, 256, 0, stream>>>(pstats, stats);

    // layer 1 (BN0+ReLU fused on the fly)
    k_fused<1><<<NBLK2, 256, 0, stream>>>(
        bucket, cnt, cf32 + 68, outA, ent_tab, flag,
        stats, par + P_GAMMA, par + P_BETA,
        WtT + 81920, par + P_BSL + DIM, outB, pstats);
    k_stats<<<125, 256, 0, stream>>>(pstats, stats + 2 * DIM);

    k_score<<<(BATCH + BATCH * NNEG) / 4, 256, 0, stream>>>(
        head, rel, tail, negi, outB, par + P_REL,
        stats + 2 * DIM, par + P_GAMMA + DIM, par + P_BETA + DIM,
        d_out, flag);
}

// Round 8
// 405.130 us; speedup vs baseline: 1.0080x; 1.0080x over previous
//
#include <hip/hip_runtime.h>
#include <stdint.h>

// Problem constants
#define N_ENTS  100000
#define N_RELS  16
#define DIM     128
#define NB      4
#define TILE_U  10240           // ushorts per WtT n-tile: 80*16*8
#define NEDGE   640000
#define BATCH   1024
#define NNEG    64
#define BN_EPS  1e-5f
#define BCAP    64              // bucket capacity per node
#define SENTR   0x01000000u     // sentinel record: rel=16 (zero coeff), src=0
#define NPB     32              // nodes per fused block
#define NBLK2   3125            // N_ENTS/NPB exact
#define CONVX_BLKS 6250
#define CONVP_BLKS 652          // ceil(P_TOTAL/256)

// converted-parameter buffer layout (ushort offsets)
#define P_REL    0        // [16][128]
#define P_BASES  2048     // [2][4][128][128]
#define P_COEFF  133120   // [2][16][4]
#define P_WSL    133248   // [2][128][128]
#define P_BSL    166016   // [2][128]
#define P_GAMMA  166272   // [2][128]
#define P_BETA   166528   // [2][128]
#define P_TOTAL  166784

typedef unsigned int uint;
typedef short short8 __attribute__((ext_vector_type(8)));
typedef float f4 __attribute__((ext_vector_type(4)));

__device__ __forceinline__ float bf2f(unsigned short u) {
    return __uint_as_float(((unsigned int)u) << 16);
}
__device__ __forceinline__ float bflo(unsigned int u) { return __uint_as_float(u << 16); }
__device__ __forceinline__ float bfhi(unsigned int u) { return __uint_as_float(u & 0xffff0000u); }
__device__ __forceinline__ unsigned short f2bf(float f) {
    unsigned int x = __float_as_uint(f);
    x += 0x7fffu + ((x >> 16) & 1u);
    return (unsigned short)(x >> 16);
}
__device__ __forceinline__ unsigned int pack2(float a, float b) {
    return (unsigned int)f2bf(a) | ((unsigned int)f2bf(b) << 16);
}

// ---------------- dtype detection (fp32 vs bf16 storage) ----------------
__device__ __forceinline__ int bf16_like(unsigned int h) {
    unsigned int m = h & 0x7FFFu;
    return (m == 0u) || (m >= 0x2D00u && m < 0x4400u);
}
__global__ __launch_bounds__(256) void k_detect(const unsigned int* __restrict__ ent,
                                                int* __restrict__ flag) {
    __shared__ int cnt[256];
    unsigned int u = ent[threadIdx.x];
    cnt[threadIdx.x] = bf16_like(u & 0xFFFFu) & bf16_like(u >> 16);
    __syncthreads();
    for (int s = 128; s > 0; s >>= 1) {
        if (threadIdx.x < s) cnt[threadIdx.x] += cnt[threadIdx.x + s];
        __syncthreads();
    }
    if (threadIdx.x == 0) flag[0] = (cnt[0] >= 140) ? 1 : 0;
}

// ---------------- merged convert: x (fp32 path only) + params ----------------
__device__ __forceinline__ unsigned short cvt1(const void* src, int i, int isbf) {
    return isbf ? ((const unsigned short*)src)[i] : f2bf(((const float*)src)[i]);
}
__global__ __launch_bounds__(256) void k_conv(
    const void* __restrict__ src, unsigned short* __restrict__ xrow,
    const void* __restrict__ rtab, const void* __restrict__ bases,
    const void* __restrict__ coeffs, const void* __restrict__ wsl,
    const void* __restrict__ bsl, const void* __restrict__ gamma,
    const void* __restrict__ beta,
    unsigned short* __restrict__ par, const int* __restrict__ flag)
{
    const int isbf = flag[0];
    if (blockIdx.x < CONVX_BLKS) {
        if (isbf) return;                        // bf16 input: ent used directly, no copy
        const int kc = threadIdx.x >> 4, r = threadIdx.x & 15;
        const int n = blockIdx.x * 16 + r;
        const size_t e0 = (size_t)n * DIM + kc * 8;
        const float4 f0 = *(const float4*)((const float*)src + e0);
        const float4 f1 = *(const float4*)((const float*)src + e0 + 4);
        uint4 w;
        w.x = pack2(f0.x, f0.y); w.y = pack2(f0.z, f0.w);
        w.z = pack2(f1.x, f1.y); w.w = pack2(f1.z, f1.w);
        *(uint4*)(xrow + e0) = w;
        return;
    }
    const int i = (blockIdx.x - CONVX_BLKS) * 256 + threadIdx.x;
    if (i >= P_TOTAL) return;
    unsigned short v;
    if      (i < P_BASES)  v = cvt1(rtab,   i - P_REL,    isbf);
    else if (i < P_COEFF)  v = cvt1(bases,  i - P_BASES,  isbf);
    else if (i < P_WSL)    v = cvt1(coeffs, i - P_COEFF,  isbf);
    else if (i < P_BSL)    v = cvt1(wsl,    i - P_WSL,    isbf);
    else if (i < P_GAMMA)  v = cvt1(bsl,    i - P_BSL,    isbf);
    else if (i < P_BETA)   v = cvt1(gamma,  i - P_GAMMA,  isbf);
    else                   v = cvt1(beta,   i - P_BETA,   isbf);
    par[i] = v;
}

// ---------------- one-kernel bucket CSR: cnt + bucket[n][64] ----------------
__global__ __launch_bounds__(256) void k_fillB(const int* __restrict__ src, const int* __restrict__ dst,
                                               const int* __restrict__ et, int* __restrict__ cnt,
                                               uint* __restrict__ bucket) {
    const int e = blockIdx.x * 256 + threadIdx.x;   // grid exact: NEDGE/256
    const int d = dst[e];
    const int p = atomicAdd(&cnt[d], 1);
    if (p < BCAP) bucket[(size_t)d * BCAP + p] = (uint)src[e] | ((uint)et[e] << 20);
}

// ---------------- WtT tiled (blocks 0..79) + fp32 coeff table (block 80) ----------------
// WtT: [l][jt 8][kc 80][r 16][8]. cf32: [2][17][4], rel=16 zero (tail mask) -> branch-free FMA
__global__ __launch_bounds__(256) void k_transw2(const unsigned short* __restrict__ par,
                                                 unsigned short* __restrict__ WtT,
                                                 float* __restrict__ cf32) {
    if (blockIdx.x == 80) {
        const int i = threadIdx.x;
        if (i < 2 * 17 * 4) {
            const int l = i / 68, rem = i - l * 68, r = rem >> 2, b = rem & 3;
            cf32[i] = (r < N_RELS) ? bf2f(par[P_COEFF + l * N_RELS * NB + r * NB + b]) : 0.f;
        }
        return;
    }
    const int i = blockIdx.x * 256 + threadIdx.x;   // blocks 0..79: 20480 items
    const int l = i / 10240;
    const int rem = i - l * 10240;
    const int jt2 = rem / 1280;
    const int rem2 = rem - jt2 * 1280;
    const int kc = rem2 >> 4, r = rem2 & 15;
    const int n = jt2 * 16 + r;
    unsigned short v[8];
#pragma unroll
    for (int e = 0; e < 8; ++e) {
        const int k = kc * 8 + e;
        v[e] = (k < DIM)
            ? par[P_WSL + l * DIM * DIM + k * DIM + n]
            : par[P_BASES + l * NB * DIM * DIM + (k - DIM) * DIM + n];
    }
    *(uint4*)(WtT + (size_t)l * 81920 + (size_t)jt2 * TILE_U + (size_t)kc * 128 + r * 8) = *(uint4*)v;
}

// ---------------- FUSED (BN of prev layer) + aggregate + GEMM + epilogue ----------------
// r6-proven geometry: 256 thr (4 waves), NPB=32. LDS A-tile [32][640] bf16, 40960B,
// swizzled byte^=(row&7)<<4. LAY template: layer-0 inner loop has NO BN ops.
// Phase 2 = r6 exact (2-node interleave, VGPR~64). r7's 4-chain (VGPR 100) regressed — keep.
// Epilogue: BN stats accumulated straight into st[] via atomicAdd (no pstats/k_stats).
// No min-waves bound: (256,8) spilled ~550MB (r3); allocator picks VGPR naturally.
template<int LAY>
__global__ __launch_bounds__(256) void k_fused(
    const uint* __restrict__ bucket, const int* __restrict__ cnt,
    const float* __restrict__ cf, const unsigned short* __restrict__ xin,
    const void* __restrict__ ent, const int* __restrict__ flag,
    const float* __restrict__ stp, const unsigned short* __restrict__ gprev,
    const unsigned short* __restrict__ bprev,
    const unsigned short* __restrict__ wtT, const unsigned short* __restrict__ bsl,
    unsigned short* __restrict__ out, float* __restrict__ st)
{
    __shared__ unsigned short Ash[NPB * 640];      // 40960 B
    const int tid = threadIdx.x;
    const int wave = tid >> 6, lane = tid & 63;
    const int n0 = blockIdx.x * NPB;
    const float inv_n = 1.0f / (float)N_ENTS;

    const unsigned short* __restrict__ xs =
        (LAY == 0 && flag[0]) ? (const unsigned short*)ent : xin;

    // per-lane BN coeffs for gather columns {2*lane, 2*lane+1} (layer 1 only)
    float gnA = 1.f, ofA = 0.f, gnB = 1.f, ofB = 0.f;
    if (LAY) {
        const int f0 = lane * 2, f1 = f0 + 1;
        const float mu0 = stp[f0] * inv_n, mu1 = stp[f1] * inv_n;
        const float va0 = stp[DIM + f0] * inv_n - mu0 * mu0;
        const float va1 = stp[DIM + f1] * inv_n - mu1 * mu1;
        gnA = bf2f(gprev[f0]) * rsqrtf(va0 + BN_EPS); ofA = bf2f(bprev[f0]) - mu0 * gnA;
        gnB = bf2f(gprev[f1]) * rsqrtf(va1 + BN_EPS); ofB = bf2f(bprev[f1]) - mu1 * gnB;
    }

    // ---- phase 1: stage self rows into LDS (k 0..127 = 256B/row), swizzled, BN-applied
    {
        const int r = tid >> 3, c = tid & 7;       // 32 rows; chunks c and c+8 (16B each)
        const size_t e0 = (size_t)(n0 + r) * DIM + c * 8;
        uint4 v0 = *(const uint4*)(xs + e0);
        uint4 v1 = *(const uint4*)(xs + e0 + 64);
        if (LAY) {
            uint vv[8] = {v0.x, v0.y, v0.z, v0.w, v1.x, v1.y, v1.z, v1.w};
#pragma unroll
            for (int p = 0; p < 8; ++p) {
                const int f0 = c * 8 + (p >> 2) * 64 + (p & 3) * 2;
                const float mu0 = stp[f0] * inv_n, mu1 = stp[f0 + 1] * inv_n;
                const float va0 = stp[DIM + f0] * inv_n - mu0 * mu0;
                const float va1 = stp[DIM + f0 + 1] * inv_n - mu1 * mu1;
                const float g0 = bf2f(gprev[f0]) * rsqrtf(va0 + BN_EPS);
                const float g1 = bf2f(gprev[f0 + 1]) * rsqrtf(va1 + BN_EPS);
                const float o0 = bf2f(bprev[f0]) - mu0 * g0;
                const float o1 = bf2f(bprev[f0 + 1]) - mu1 * g1;
                const float w0 = fmaxf(fmaf(bflo(vv[p]), g0, o0), 0.f);
                const float w1 = fmaxf(fmaf(bfhi(vv[p]), g1, o1), 0.f);
                vv[p] = pack2(w0, w1);
            }
            v0.x = vv[0]; v0.y = vv[1]; v0.z = vv[2]; v0.w = vv[3];
            v1.x = vv[4]; v1.y = vv[5]; v1.z = vv[6]; v1.w = vv[7];
        }
        const int byte0 = (r * 1280 + c * 16) ^ ((r & 7) << 4);
        *(uint4*)((char*)Ash + byte0) = v0;
        *(uint4*)((char*)Ash + byte0 + 128) = v1;   // +128: bit7 only, outside XOR bits 4-6
    }

    // ---- phase 2 (r6-proven): gather-aggregate, 2-node interleave, SGPR-base gathers
    const uint* __restrict__ x32 = (const uint*)xs;
    const int mybase = n0 + wave * 8;
    for (int pr = 0; pr < 4; ++pr) {
        const int na = mybase + pr * 2;
        int ca = cnt[na];     if (ca > BCAP) ca = BCAP;
        int cb = cnt[na + 1]; if (cb > BCAP) cb = BCAP;
        const int qm = ((ca > cb ? ca : cb) + 7) >> 3;
        float aLo[2][NB] = {{0.f,0.f,0.f,0.f},{0.f,0.f,0.f,0.f}};
        float aHi[2][NB] = {{0.f,0.f,0.f,0.f},{0.f,0.f,0.f,0.f}};
        const uint4* __restrict__ bk = (const uint4*)(bucket + (size_t)na * BCAP);
        for (int j = 0; j < qm; ++j) {
            uint rec[2][8];
            uint xw[2][8];
            const int b8 = j * 8;
#pragma unroll
            for (int h = 0; h < 2; ++h) {
                const int cn = h ? cb : ca;
                if (b8 < cn) {
                    const uint4 r0 = bk[h * 16 + j * 2];
                    const uint4 r1 = bk[h * 16 + j * 2 + 1];
                    rec[h][0] = r0.x; rec[h][1] = r0.y; rec[h][2] = r0.z; rec[h][3] = r0.w;
                    rec[h][4] = r1.x; rec[h][5] = r1.y; rec[h][6] = r1.z; rec[h][7] = r1.w;
#pragma unroll
                    for (int s = 0; s < 8; ++s) {
                        uint rr = (uint)__builtin_amdgcn_readfirstlane((int)rec[h][s]);
                        if (b8 + s >= cn) rr = SENTR;        // uniform tail mask
                        rec[h][s] = rr;                      // uniform -> SGPR base
                        xw[h][s] = x32[(size_t)(rr & 0xFFFFFu) * 64 + lane];
                    }
                }
            }
#pragma unroll
            for (int h = 0; h < 2; ++h) {
                const int cn = h ? cb : ca;
                if (b8 < cn) {
#pragma unroll
                    for (int s = 0; s < 8; ++s) {
                        const int rel = (int)(rec[h][s] >> 20);   // uniform; 16 -> zero coeffs
                        const float4 cc = *(const float4*)(cf + rel * 4);  // s_load_dwordx4
                        float xl, xh;
                        if (LAY) {
                            xl = fmaxf(fmaf(bflo(xw[h][s]), gnA, ofA), 0.f);
                            xh = fmaxf(fmaf(bfhi(xw[h][s]), gnB, ofB), 0.f);
                        } else {
                            xl = bflo(xw[h][s]);
                            xh = bfhi(xw[h][s]);
                        }
                        aLo[h][0] = fmaf(cc.x, xl, aLo[h][0]);
                        aHi[h][0] = fmaf(cc.x, xh, aHi[h][0]);
                        aLo[h][1] = fmaf(cc.y, xl, aLo[h][1]);
                        aHi[h][1] = fmaf(cc.y, xh, aHi[h][1]);
                        aLo[h][2] = fmaf(cc.z, xl, aLo[h][2]);
                        aHi[h][2] = fmaf(cc.z, xh, aHi[h][2]);
                        aLo[h][3] = fmaf(cc.w, xl, aLo[h][3]);
                        aHi[h][3] = fmaf(cc.w, xh, aHi[h][3]);
                    }
                }
            }
        }
#pragma unroll
        for (int h = 0; h < 2; ++h) {
            const int ra = wave * 8 + pr * 2 + h;
            const int swz = (ra & 7) << 4;
#pragma unroll
            for (int b = 0; b < NB; ++b) {
                // A[ra][128 + b*128 + 2*lane .. +1]  (bank-conflict-free: lane*4 stride)
                const int byte = (ra * 1280 + 256 + b * 256 + lane * 4) ^ swz;
                *(uint*)((char*)Ash + byte) = pack2(aLo[h][b], aHi[h][b]);
            }
        }
    }

    // ---- phase 3: MFMA. wave w: m-tiles {0,1} x n-tiles {2w,2w+1}, K=640 (20 steps)
    const int quad = lane >> 4, l16 = lane & 15;
    f4 acc[2][2];
#pragma unroll
    for (int i = 0; i < 2; ++i)
#pragma unroll
        for (int j = 0; j < 2; ++j)
#pragma unroll
            for (int r = 0; r < 4; ++r) acc[i][j][r] = 0.f;

    const unsigned short* __restrict__ pB0 = wtT + (size_t)(2 * wave) * TILE_U + quad * 128 + l16 * 8;
    const unsigned short* __restrict__ pB1 = pB0 + TILE_U;
    const char* Ab = (const char*)Ash;
    const int swz = (l16 & 7) << 4;
    // even/odd ks bases: XOR touches bits 4-6 and ks*64 carries bit 6 -> two bases
    const int b0e = (l16 * 1280 + quad * 16) ^ swz;
    const int b0o = (l16 * 1280 + 64 + quad * 16) ^ swz;
    const int b1e = ((l16 + 16) * 1280 + quad * 16) ^ swz;
    const int b1o = ((l16 + 16) * 1280 + 64 + quad * 16) ^ swz;

    short8 xa0, xa1, xb0, xb1, ya0, ya1, yb0, yb1;
#define FLDA(P, s) \
    P##a0 = *(const short8*)(Ab + (((s) & 1) ? b0o : b0e) + ((s) >> 1) * 128); \
    P##a1 = *(const short8*)(Ab + (((s) & 1) ? b1o : b1e) + ((s) >> 1) * 128);
#define FLDB(P, s) \
    P##b0 = *(const short8*)(pB0 + (s) * 512); \
    P##b1 = *(const short8*)(pB1 + (s) * 512);
#define FLD(P, s) FLDA(P, s) FLDB(P, s)
#define FMM(P) \
    acc[0][0] = __builtin_amdgcn_mfma_f32_16x16x32_bf16(P##a0, P##b0, acc[0][0], 0, 0, 0); \
    acc[0][1] = __builtin_amdgcn_mfma_f32_16x16x32_bf16(P##a0, P##b1, acc[0][1], 0, 0, 0); \
    acc[1][0] = __builtin_amdgcn_mfma_f32_16x16x32_bf16(P##a1, P##b0, acc[1][0], 0, 0, 0); \
    acc[1][1] = __builtin_amdgcn_mfma_f32_16x16x32_bf16(P##a1, P##b1, acc[1][1], 0, 0, 0);

    // B loads are global (no LDS dependency): issue before the barrier
    FLDB(x, 0) FLDB(y, 1)
    __syncthreads();
    FLDA(x, 0) FLDA(y, 1)
    FMM(x) FLD(x, 2)
    FMM(y) FLD(y, 3)
    FMM(x) FLD(x, 4)
    FMM(y) FLD(y, 5)
    FMM(x) FLD(x, 6)
    FMM(y) FLD(y, 7)
    FMM(x) FLD(x, 8)
    FMM(y) FLD(y, 9)
    FMM(x) FLD(x, 10)
    FMM(y) FLD(y, 11)
    FMM(x) FLD(x, 12)
    FMM(y) FLD(y, 13)
    FMM(x) FLD(x, 14)
    FMM(y) FLD(y, 15)
    FMM(x) FLD(x, 16)
    FMM(y) FLD(y, 17)
    FMM(x) FLD(x, 18)
    FMM(y) FLD(y, 19)
    FMM(x)
    FMM(y)
#undef FLDA
#undef FLDB
#undef FLD
#undef FMM

    // ---- epilogue: o = (acc + bias)/deg, bf16 store, BN stats straight to st via atomics
    float ssum[2] = {0.f, 0.f}, sssq[2] = {0.f, 0.f};
#pragma unroll
    for (int m = 0; m < 2; ++m) {
#pragma unroll
        for (int r = 0; r < 4; ++r) {
            const int row = n0 + m * 16 + quad * 4 + r;    // always < N_ENTS (3125*32 exact)
            const float rdeg = 1.0f / fmaxf((float)cnt[row], 1.0f);
#pragma unroll
            for (int n = 0; n < 2; ++n) {
                const int col = (2 * wave + n) * 16 + l16;
                const float o = (acc[m][n][r] + bf2f(bsl[col])) * rdeg;
                out[(size_t)row * DIM + col] = f2bf(o);
                ssum[n] += o;
                sssq[n] += o * o;
            }
        }
    }
#pragma unroll
    for (int n = 0; n < 2; ++n) {
        float s = ssum[n], q2 = sssq[n];
        s += __shfl_xor(s, 16, 64);  s += __shfl_xor(s, 32, 64);
        q2 += __shfl_xor(q2, 16, 64); q2 += __shfl_xor(q2, 32, 64);
        if (quad == 0) {
            const int col = (2 * wave + n) * 16 + l16;
            atomicAdd(&st[col], s);
            atomicAdd(&st[DIM + col], q2);
        }
    }
}

// ---------------- fused scoring: BN1+ReLU applied to gathered embeddings ----------------
__global__ __launch_bounds__(256) void k_score(
    const int* __restrict__ head, const int* __restrict__ rel,
    const int* __restrict__ tail, const int* __restrict__ negi,
    const unsigned short* __restrict__ emb, const unsigned short* __restrict__ rtab,
    const float* __restrict__ st1, const unsigned short* __restrict__ gm1,
    const unsigned short* __restrict__ bt1,
    void* __restrict__ outp, const int* __restrict__ flag)
{
    const int wave = threadIdx.x >> 6, lane = threadIdx.x & 63;
    const int w = blockIdx.x * 4 + wave;   // grid exact: (BATCH + BATCH*NNEG)/4
    const float inv_n = 1.0f / (float)N_ENTS;
    const int f0 = lane * 2, f1 = f0 + 1;
    const float mu0 = st1[f0] * inv_n, mu1 = st1[f1] * inv_n;
    const float va0 = st1[DIM + f0] * inv_n - mu0 * mu0;
    const float va1 = st1[DIM + f1] * inv_n - mu1 * mu1;
    const float g0 = bf2f(gm1[f0]) * rsqrtf(va0 + BN_EPS);
    const float g1 = bf2f(gm1[f1]) * rsqrtf(va1 + BN_EPS);
    const float o0 = bf2f(bt1[f0]) - mu0 * g0;
    const float o1 = bf2f(bt1[f1]) - mu1 * g1;

    int i, t;
    if (w < BATCH) { i = w; t = tail[w]; }
    else { const int w2 = w - BATCH; i = w2 >> 6; t = negi[w2]; }
    const uint hv = ((const uint*)emb)[(size_t)head[i] * 64 + lane];
    const uint rv = ((const uint*)rtab)[(size_t)rel[i] * 64 + lane];
    const uint tv = ((const uint*)emb)[(size_t)t * 64 + lane];
    const float h0 = fmaxf(fmaf(bflo(hv), g0, o0), 0.f);
    const float h1 = fmaxf(fmaf(bfhi(hv), g1, o1), 0.f);
    const float t0 = fmaxf(fmaf(bflo(tv), g0, o0), 0.f);
    const float t1 = fmaxf(fmaf(bfhi(tv), g1, o1), 0.f);
    const float d0 = (h0 + bflo(rv)) - t0;
    const float d1 = (h1 + bfhi(rv)) - t1;
    float s = d0 * d0 + d1 * d1;
#pragma unroll
    for (int m = 32; m >= 1; m >>= 1) s += __shfl_xor(s, m, 64);
    if (lane == 0) {
        const float v = -sqrtf(s);
        if (flag[0]) ((unsigned short*)outp)[w] = f2bf(v);
        else         ((float*)outp)[w] = v;
    }
}

extern "C" void kernel_launch(void* const* d_in, const int* in_sizes, int n_in,
                              void* d_out, int out_size, void* d_ws, size_t ws_size,
                              hipStream_t stream)
{
    const int* head = (const int*)d_in[0];
    const int* rel  = (const int*)d_in[1];
    const int* tail = (const int*)d_in[2];
    const int* negi = (const int*)d_in[3];
    const int* eidx = (const int*)d_in[4];
    const int* etyp = (const int*)d_in[5];
    const void* ent_tab = d_in[6];
    const void* rtab_in = d_in[7];
    const void* bases_in = d_in[8];
    const void* coeffs_in = d_in[9];
    const void* wsl_in = d_in[10];
    const void* bsl_in = d_in[11];
    const void* gamma_in = d_in[12];
    const void* beta_in = d_in[13];

    char* ws = (char*)d_ws;
    size_t off = 0;
    auto alloc = [&](size_t bytes) -> char* {
        char* p = ws + off;
        off += (bytes + 511) & ~(size_t)511;
        return p;
    };
    int* flag            = (int*)alloc(4);
    int* cnt             = (int*)alloc((size_t)N_ENTS * 4);
    uint* bucket         = (uint*)alloc((size_t)N_ENTS * BCAP * 4);             // 25.6 MB
    unsigned short* xrow = (unsigned short*)alloc((size_t)N_ENTS * DIM * 2);    // fp32-input path only
    unsigned short* outA = (unsigned short*)alloc((size_t)N_ENTS * DIM * 2);    // layer-0 raw out
    unsigned short* outB = (unsigned short*)alloc((size_t)N_ENTS * DIM * 2);    // layer-1 raw out
    unsigned short* par  = (unsigned short*)alloc((size_t)P_TOTAL * 2);
    unsigned short* WtT  = (unsigned short*)alloc((size_t)2 * 81920 * 2);
    float* cf32          = (float*)alloc((size_t)2 * 17 * 4 * 4);
    float* stats         = (float*)alloc(2 * 2 * DIM * 4);
    (void)ws_size; (void)in_sizes; (void)n_in; (void)out_size;

    const int* esrc = eidx;
    const int* edst = eidx + NEDGE;

    k_detect<<<1, 256, 0, stream>>>((const unsigned int*)ent_tab, flag);

    k_conv<<<CONVX_BLKS + CONVP_BLKS, 256, 0, stream>>>(
        ent_tab, xrow, rtab_in, bases_in, coeffs_in, wsl_in, bsl_in, gamma_in, beta_in,
        par, flag);
    k_transw2<<<81, 256, 0, stream>>>(par, WtT, cf32);

    hipMemsetAsync(cnt, 0, (size_t)N_ENTS * 4, stream);
    hipMemsetAsync(stats, 0, 2 * 2 * DIM * 4, stream);

    k_fillB<<<NEDGE / 256, 256, 0, stream>>>(esrc, edst, etyp, cnt, bucket);

    // layer 0 (no BN on input) — stats accumulated in-kernel to stats[0..255]
    k_fused<0><<<NBLK2, 256, 0, stream>>>(
        bucket, cnt, cf32, xrow, ent_tab, flag,
        stats, par + P_GAMMA, par + P_BETA,          // unused at LAY=0
        WtT, par + P_BSL, outA, stats);

    // layer 1 (BN0+ReLU fused on the fly) — stats to stats[256..511]
    k_fused<1><<<NBLK2, 256, 0, stream>>>(
        bucket, cnt, cf32 + 68, outA, ent_tab, flag,
        stats, par + P_GAMMA, par + P_BETA,
        WtT + 81920, par + P_BSL + DIM, outB, stats + 2 * DIM);

    k_score<<<(BATCH + BATCH * NNEG) / 4, 256, 0, stream>>>(
        head, rel, tail, negi, outB, par + P_REL,
        stats + 2 * DIM, par + P_GAMMA + DIM, par + P_BETA + DIM,
        d_out, flag);
}

// Round 9
// 363.106 us; speedup vs baseline: 1.1247x; 1.1157x over previous
//
#include <hip/hip_runtime.h>
#include <stdint.h>

// Problem constants
#define N_ENTS  100000
#define N_RELS  16
#define DIM     128
#define NB      4
#define TILE_U  10240           // ushorts per WtT n-tile: 80*16*8
#define NEDGE   640000
#define BATCH   1024
#define NNEG    64
#define BN_EPS  1e-5f
#define BCAP    64              // bucket capacity per node
#define SENTR   0x01000000u     // sentinel record: rel=16 (zero coeff), src=0
#define NPB     32              // nodes per fused block
#define NBLK2   3125            // N_ENTS/NPB exact

// merged k_conv block ranges
#define B_X     0               // [0,6250): x fp32->bf16 (early-exit if bf16)
#define B_CNT   6250            // [6250,6348): zero cnt (98 blocks of uint4)
#define B_TW    6348            // [6348,6428): WtT build from RAW inputs (80 blocks)
#define B_CF    6428            // cf32 table (1 block)
#define B_PAR   6429            // [6429,6440): small param convert (2816 elems)
#define B_GRID  6440

// converted-parameter buffer layout (ushort offsets) — only small params now
#define P_REL    0        // [16][128]
#define P_BSL    2048     // [2][128]
#define P_GAMMA  2304     // [2][128]
#define P_BETA   2560     // [2][128]
#define P_TOTAL  2816

typedef unsigned int uint;
typedef short short8 __attribute__((ext_vector_type(8)));
typedef float f4 __attribute__((ext_vector_type(4)));

__device__ __forceinline__ float bf2f(unsigned short u) {
    return __uint_as_float(((unsigned int)u) << 16);
}
__device__ __forceinline__ float bflo(unsigned int u) { return __uint_as_float(u << 16); }
__device__ __forceinline__ float bfhi(unsigned int u) { return __uint_as_float(u & 0xffff0000u); }
__device__ __forceinline__ unsigned short f2bf(float f) {
    unsigned int x = __float_as_uint(f);
    x += 0x7fffu + ((x >> 16) & 1u);
    return (unsigned short)(x >> 16);
}
__device__ __forceinline__ unsigned int pack2(float a, float b) {
    return (unsigned int)f2bf(a) | ((unsigned int)f2bf(b) << 16);
}

// ---------------- dtype detection (fp32 vs bf16 storage) + stats zero ----------------
__device__ __forceinline__ int bf16_like(unsigned int h) {
    unsigned int m = h & 0x7FFFu;
    return (m == 0u) || (m >= 0x2D00u && m < 0x4400u);
}
__global__ __launch_bounds__(256) void k_detect(const unsigned int* __restrict__ ent,
                                                int* __restrict__ flag,
                                                float* __restrict__ stats) {
    __shared__ int cnt[256];
    unsigned int u = ent[threadIdx.x];
    cnt[threadIdx.x] = bf16_like(u & 0xFFFFu) & bf16_like(u >> 16);
    stats[threadIdx.x] = 0.f;                      // zero stats[512] inline
    stats[256 + threadIdx.x] = 0.f;
    __syncthreads();
    for (int s = 128; s > 0; s >>= 1) {
        if (threadIdx.x < s) cnt[threadIdx.x] += cnt[threadIdx.x + s];
        __syncthreads();
    }
    if (threadIdx.x == 0) flag[0] = (cnt[0] >= 140) ? 1 : 0;
}

// ---------------- merged convert/setup kernel ----------------
// x convert (fp32 path), cnt zero, WtT build (from raw inputs), cf32, small params.
__device__ __forceinline__ unsigned short cvt1(const void* src, int i, int isbf) {
    return isbf ? ((const unsigned short*)src)[i] : f2bf(((const float*)src)[i]);
}
__global__ __launch_bounds__(256) void k_conv(
    const void* __restrict__ src, unsigned short* __restrict__ xrow,
    const void* __restrict__ rtab, const void* __restrict__ bases,
    const void* __restrict__ coeffs, const void* __restrict__ wsl,
    const void* __restrict__ bsl, const void* __restrict__ gamma,
    const void* __restrict__ beta,
    unsigned short* __restrict__ par, unsigned short* __restrict__ WtT,
    float* __restrict__ cf32, int* __restrict__ cnt, const int* __restrict__ flag)
{
    const int b = blockIdx.x;
    const int isbf = flag[0];
    if (b < B_CNT) {                               // ---- x conversion
        if (isbf) return;                          // bf16 input: ent used directly
        const int kc = threadIdx.x >> 4, r = threadIdx.x & 15;
        const int n = b * 16 + r;
        const size_t e0 = (size_t)n * DIM + kc * 8;
        const float4 f0 = *(const float4*)((const float*)src + e0);
        const float4 f1 = *(const float4*)((const float*)src + e0 + 4);
        uint4 w;
        w.x = pack2(f0.x, f0.y); w.y = pack2(f0.z, f0.w);
        w.z = pack2(f1.x, f1.y); w.w = pack2(f1.z, f1.w);
        *(uint4*)(xrow + e0) = w;
        return;
    }
    if (b < B_TW) {                                // ---- zero cnt via uint4 stores
        const int i = (b - B_CNT) * 256 + threadIdx.x;   // uint4 index
        if (i < N_ENTS / 4) {
            uint4 z = {0, 0, 0, 0};
            ((uint4*)cnt)[i] = z;
        }
        return;
    }
    if (b < B_CF) {                                // ---- WtT from RAW wsl/bases
        const int i = (b - B_TW) * 256 + threadIdx.x;    // [0, 20480)
        const int l = i / 10240;
        const int rem = i - l * 10240;
        const int jt2 = rem / 1280;
        const int rem2 = rem - jt2 * 1280;
        const int kc = rem2 >> 4, r = rem2 & 15;
        const int n = jt2 * 16 + r;
        unsigned short v[8];
#pragma unroll
        for (int e = 0; e < 8; ++e) {
            const int k = kc * 8 + e;
            v[e] = (k < DIM)
                ? cvt1(wsl,   l * DIM * DIM + k * DIM + n, isbf)
                : cvt1(bases, l * NB * DIM * DIM + (k - DIM) * DIM + n, isbf);
        }
        *(uint4*)(WtT + (size_t)l * 81920 + (size_t)jt2 * TILE_U + (size_t)kc * 128 + r * 8) = *(uint4*)v;
        return;
    }
    if (b == B_CF) {                               // ---- cf32 [2][17][4], rel=16 -> 0
        const int i = threadIdx.x;
        if (i < 2 * 17 * 4) {
            const int l = i / 68, rem = i - l * 68, r = rem >> 2, bb = rem & 3;
            const int idx = l * N_RELS * NB + r * NB + bb;
            cf32[i] = (r < N_RELS)
                ? (isbf ? bf2f(((const unsigned short*)coeffs)[idx])
                        : ((const float*)coeffs)[idx])
                : 0.f;
        }
        return;
    }
    // ---- small params: rel, bsl, gamma, beta
    const int i = (b - B_PAR) * 256 + threadIdx.x;
    if (i >= P_TOTAL) return;
    unsigned short v;
    if      (i < P_BSL)    v = cvt1(rtab,  i - P_REL,   isbf);
    else if (i < P_GAMMA)  v = cvt1(bsl,   i - P_BSL,   isbf);
    else if (i < P_BETA)   v = cvt1(gamma, i - P_GAMMA, isbf);
    else                   v = cvt1(beta,  i - P_BETA,  isbf);
    par[i] = v;
}

// ---------------- one-kernel bucket CSR: cnt + bucket[n][64] ----------------
__global__ __launch_bounds__(256) void k_fillB(const int* __restrict__ src, const int* __restrict__ dst,
                                               const int* __restrict__ et, int* __restrict__ cnt,
                                               uint* __restrict__ bucket) {
    const int e = blockIdx.x * 256 + threadIdx.x;   // grid exact: NEDGE/256
    const int d = dst[e];
    const int p = atomicAdd(&cnt[d], 1);
    if (p < BCAP) bucket[(size_t)d * BCAP + p] = (uint)src[e] | ((uint)et[e] << 20);
}

// ---------------- FUSED (BN of prev layer) + aggregate + GEMM + epilogue ----------------
// r6-PROVEN kernel, byte-identical structure: 256 thr (4 waves), NPB=32, runtime lay,
// pstats epilogue. LDS A-tile [32][640] bf16 40960B, swizzle byte^=(row&7)<<4.
// DO NOT: min-waves 8 (r3 spill), 4-chain interleave (r7 VGPR 100), atomic stats (r8
// contention), LAY template (r8 codegen perturbation). All measured regressions.
__global__ __launch_bounds__(256, 4) void k_fused(
    const uint* __restrict__ bucket, const int* __restrict__ cnt,
    const float* __restrict__ cf, const unsigned short* __restrict__ xin,
    const void* __restrict__ ent, const int* __restrict__ flag, const int lay,
    const float* __restrict__ stp, const unsigned short* __restrict__ gprev,
    const unsigned short* __restrict__ bprev,
    const unsigned short* __restrict__ wtT, const unsigned short* __restrict__ bsl,
    unsigned short* __restrict__ out, float* __restrict__ pstats)
{
    __shared__ unsigned short Ash[NPB * 640];      // 40960 B
    const int tid = threadIdx.x;
    const int wave = tid >> 6, lane = tid & 63;
    const int n0 = blockIdx.x * NPB;
    const float inv_n = 1.0f / (float)N_ENTS;

    const unsigned short* __restrict__ xs =
        (lay == 0 && flag[0]) ? (const unsigned short*)ent : xin;

    // per-lane BN coeffs for gather columns {2*lane, 2*lane+1} (identity for lay 0)
    float gnA = 1.f, ofA = 0.f, gnB = 1.f, ofB = 0.f;
    if (lay) {
        const int f0 = lane * 2, f1 = f0 + 1;
        const float mu0 = stp[f0] * inv_n, mu1 = stp[f1] * inv_n;
        const float va0 = stp[DIM + f0] * inv_n - mu0 * mu0;
        const float va1 = stp[DIM + f1] * inv_n - mu1 * mu1;
        gnA = bf2f(gprev[f0]) * rsqrtf(va0 + BN_EPS); ofA = bf2f(bprev[f0]) - mu0 * gnA;
        gnB = bf2f(gprev[f1]) * rsqrtf(va1 + BN_EPS); ofB = bf2f(bprev[f1]) - mu1 * gnB;
    }

    // ---- phase 1: stage self rows into LDS (k 0..127 = 256B/row), swizzled, BN-applied
    {
        const int r = tid >> 3, c = tid & 7;       // 32 rows; chunks c and c+8 (16B each)
        const size_t e0 = (size_t)(n0 + r) * DIM + c * 8;
        uint4 v0 = *(const uint4*)(xs + e0);
        uint4 v1 = *(const uint4*)(xs + e0 + 64);
        if (lay) {
            uint vv[8] = {v0.x, v0.y, v0.z, v0.w, v1.x, v1.y, v1.z, v1.w};
#pragma unroll
            for (int p = 0; p < 8; ++p) {
                const int f0 = c * 8 + (p >> 2) * 64 + (p & 3) * 2;
                const float mu0 = stp[f0] * inv_n, mu1 = stp[f0 + 1] * inv_n;
                const float va0 = stp[DIM + f0] * inv_n - mu0 * mu0;
                const float va1 = stp[DIM + f0 + 1] * inv_n - mu1 * mu1;
                const float g0 = bf2f(gprev[f0]) * rsqrtf(va0 + BN_EPS);
                const float g1 = bf2f(gprev[f0 + 1]) * rsqrtf(va1 + BN_EPS);
                const float o0 = bf2f(bprev[f0]) - mu0 * g0;
                const float o1 = bf2f(bprev[f0 + 1]) - mu1 * g1;
                const float w0 = fmaxf(fmaf(bflo(vv[p]), g0, o0), 0.f);
                const float w1 = fmaxf(fmaf(bfhi(vv[p]), g1, o1), 0.f);
                vv[p] = pack2(w0, w1);
            }
            v0.x = vv[0]; v0.y = vv[1]; v0.z = vv[2]; v0.w = vv[3];
            v1.x = vv[4]; v1.y = vv[5]; v1.z = vv[6]; v1.w = vv[7];
        }
        const int byte0 = (r * 1280 + c * 16) ^ ((r & 7) << 4);
        *(uint4*)((char*)Ash + byte0) = v0;
        *(uint4*)((char*)Ash + byte0 + 128) = v1;   // +128: bit7 only, outside XOR bits 4-6
    }

    // ---- phase 2: gather-aggregate (wave-uniform records -> SGPR base gathers)
    const uint* __restrict__ x32 = (const uint*)xs;
    const int mybase = n0 + wave * 8;
    for (int pr = 0; pr < 4; ++pr) {
        const int na = mybase + pr * 2;
        int ca = cnt[na];     if (ca > BCAP) ca = BCAP;
        int cb = cnt[na + 1]; if (cb > BCAP) cb = BCAP;
        const int qm = ((ca > cb ? ca : cb) + 7) >> 3;
        float aLo[2][NB] = {{0.f,0.f,0.f,0.f},{0.f,0.f,0.f,0.f}};
        float aHi[2][NB] = {{0.f,0.f,0.f,0.f},{0.f,0.f,0.f,0.f}};
        const uint4* __restrict__ bk = (const uint4*)(bucket + (size_t)na * BCAP);
        for (int j = 0; j < qm; ++j) {
            uint rec[2][8];
            uint xw[2][8];
            const int b8 = j * 8;
#pragma unroll
            for (int h = 0; h < 2; ++h) {
                const int cn = h ? cb : ca;
                if (b8 < cn) {
                    const uint4 r0 = bk[h * 16 + j * 2];
                    const uint4 r1 = bk[h * 16 + j * 2 + 1];
                    rec[h][0] = r0.x; rec[h][1] = r0.y; rec[h][2] = r0.z; rec[h][3] = r0.w;
                    rec[h][4] = r1.x; rec[h][5] = r1.y; rec[h][6] = r1.z; rec[h][7] = r1.w;
#pragma unroll
                    for (int s = 0; s < 8; ++s) {
                        uint rr = (uint)__builtin_amdgcn_readfirstlane((int)rec[h][s]);
                        if (b8 + s >= cn) rr = SENTR;        // uniform tail mask
                        rec[h][s] = rr;                      // uniform -> SGPR base
                        xw[h][s] = x32[(size_t)(rr & 0xFFFFFu) * 64 + lane];
                    }
                }
            }
#pragma unroll
            for (int h = 0; h < 2; ++h) {
                const int cn = h ? cb : ca;
                if (b8 < cn) {
#pragma unroll
                    for (int s = 0; s < 8; ++s) {
                        const int rel = (int)(rec[h][s] >> 20);   // uniform; 16 -> zero coeffs
                        const float4 cc = *(const float4*)(cf + rel * 4);  // s_load_dwordx4
                        float xl, xh;
                        if (lay) {
                            xl = fmaxf(fmaf(bflo(xw[h][s]), gnA, ofA), 0.f);
                            xh = fmaxf(fmaf(bfhi(xw[h][s]), gnB, ofB), 0.f);
                        } else {
                            xl = bflo(xw[h][s]);
                            xh = bfhi(xw[h][s]);
                        }
                        aLo[h][0] = fmaf(cc.x, xl, aLo[h][0]);
                        aHi[h][0] = fmaf(cc.x, xh, aHi[h][0]);
                        aLo[h][1] = fmaf(cc.y, xl, aLo[h][1]);
                        aHi[h][1] = fmaf(cc.y, xh, aHi[h][1]);
                        aLo[h][2] = fmaf(cc.z, xl, aLo[h][2]);
                        aHi[h][2] = fmaf(cc.z, xh, aHi[h][2]);
                        aLo[h][3] = fmaf(cc.w, xl, aLo[h][3]);
                        aHi[h][3] = fmaf(cc.w, xh, aHi[h][3]);
                    }
                }
            }
        }
#pragma unroll
        for (int h = 0; h < 2; ++h) {
            const int ra = wave * 8 + pr * 2 + h;
            const int swz = (ra & 7) << 4;
#pragma unroll
            for (int b = 0; b < NB; ++b) {
                // A[ra][128 + b*128 + 2*lane .. +1]  (bank-conflict-free: lane*4 stride)
                const int byte = (ra * 1280 + 256 + b * 256 + lane * 4) ^ swz;
                *(uint*)((char*)Ash + byte) = pack2(aLo[h][b], aHi[h][b]);
            }
        }
    }

    // ---- phase 3: MFMA. wave w: m-tiles {0,1} x n-tiles {2w,2w+1}, K=640 (20 steps)
    const int quad = lane >> 4, l16 = lane & 15;
    f4 acc[2][2];
#pragma unroll
    for (int i = 0; i < 2; ++i)
#pragma unroll
        for (int j = 0; j < 2; ++j)
#pragma unroll
            for (int r = 0; r < 4; ++r) acc[i][j][r] = 0.f;

    const unsigned short* __restrict__ pB0 = wtT + (size_t)(2 * wave) * TILE_U + quad * 128 + l16 * 8;
    const unsigned short* __restrict__ pB1 = pB0 + TILE_U;
    const char* Ab = (const char*)Ash;
    const int swz = (l16 & 7) << 4;
    // even/odd ks bases: XOR touches bits 4-6 and ks*64 carries bit 6 -> two bases
    const int b0e = (l16 * 1280 + quad * 16) ^ swz;
    const int b0o = (l16 * 1280 + 64 + quad * 16) ^ swz;
    const int b1e = ((l16 + 16) * 1280 + quad * 16) ^ swz;
    const int b1o = ((l16 + 16) * 1280 + 64 + quad * 16) ^ swz;

    short8 xa0, xa1, xb0, xb1, ya0, ya1, yb0, yb1;
#define FLDA(P, s) \
    P##a0 = *(const short8*)(Ab + (((s) & 1) ? b0o : b0e) + ((s) >> 1) * 128); \
    P##a1 = *(const short8*)(Ab + (((s) & 1) ? b1o : b1e) + ((s) >> 1) * 128);
#define FLDB(P, s) \
    P##b0 = *(const short8*)(pB0 + (s) * 512); \
    P##b1 = *(const short8*)(pB1 + (s) * 512);
#define FLD(P, s) FLDA(P, s) FLDB(P, s)
#define FMM(P) \
    acc[0][0] = __builtin_amdgcn_mfma_f32_16x16x32_bf16(P##a0, P##b0, acc[0][0], 0, 0, 0); \
    acc[0][1] = __builtin_amdgcn_mfma_f32_16x16x32_bf16(P##a0, P##b1, acc[0][1], 0, 0, 0); \
    acc[1][0] = __builtin_amdgcn_mfma_f32_16x16x32_bf16(P##a1, P##b0, acc[1][0], 0, 0, 0); \
    acc[1][1] = __builtin_amdgcn_mfma_f32_16x16x32_bf16(P##a1, P##b1, acc[1][1], 0, 0, 0);

    // B loads are global (no LDS dependency): issue before the barrier
    FLDB(x, 0) FLDB(y, 1)
    __syncthreads();
    FLDA(x, 0) FLDA(y, 1)
    FMM(x) FLD(x, 2)
    FMM(y) FLD(y, 3)
    FMM(x) FLD(x, 4)
    FMM(y) FLD(y, 5)
    FMM(x) FLD(x, 6)
    FMM(y) FLD(y, 7)
    FMM(x) FLD(x, 8)
    FMM(y) FLD(y, 9)
    FMM(x) FLD(x, 10)
    FMM(y) FLD(y, 11)
    FMM(x) FLD(x, 12)
    FMM(y) FLD(y, 13)
    FMM(x) FLD(x, 14)
    FMM(y) FLD(y, 15)
    FMM(x) FLD(x, 16)
    FMM(y) FLD(y, 17)
    FMM(x) FLD(x, 18)
    FMM(y) FLD(y, 19)
    FMM(x)
    FMM(y)
#undef FLDA
#undef FLDB
#undef FLD
#undef FMM

    // ---- epilogue: o = (acc + bias)/deg, bf16 store, per-block BN partial stats
    float ssum[2] = {0.f, 0.f}, sssq[2] = {0.f, 0.f};
#pragma unroll
    for (int m = 0; m < 2; ++m) {
#pragma unroll
        for (int r = 0; r < 4; ++r) {
            const int row = n0 + m * 16 + quad * 4 + r;    // always < N_ENTS (3125*32 exact)
            const float rdeg = 1.0f / fmaxf((float)cnt[row], 1.0f);
#pragma unroll
            for (int n = 0; n < 2; ++n) {
                const int col = (2 * wave + n) * 16 + l16;
                const float o = (acc[m][n][r] + bf2f(bsl[col])) * rdeg;
                out[(size_t)row * DIM + col] = f2bf(o);
                ssum[n] += o;
                sssq[n] += o * o;
            }
        }
    }
#pragma unroll
    for (int n = 0; n < 2; ++n) {
        float s = ssum[n], q2 = sssq[n];
        s += __shfl_xor(s, 16, 64);  s += __shfl_xor(s, 32, 64);
        q2 += __shfl_xor(q2, 16, 64); q2 += __shfl_xor(q2, 32, 64);
        if (quad == 0) {
            const int col = (2 * wave + n) * 16 + l16;
            pstats[(size_t)blockIdx.x * 256 + col] = s;
            pstats[(size_t)blockIdx.x * 256 + 128 + col] = q2;
        }
    }
}

// ---------------- reduce per-block stats -> st[256] ----------------
__global__ __launch_bounds__(256) void k_stats(const float* __restrict__ pstats,
                                               float* __restrict__ st) {
    const int o = threadIdx.x;
    const int b0 = blockIdx.x * 25;                // grid 125: 125*25 = 3125 exact
    float s = 0.f;
    for (int b = b0; b < b0 + 25; ++b)
        s += pstats[(size_t)b * 256 + o];
    atomicAdd(&st[o], s);
}

// ---------------- fused scoring: BN1+ReLU applied to gathered embeddings ----------------
__global__ __launch_bounds__(256) void k_score(
    const int* __restrict__ head, const int* __restrict__ rel,
    const int* __restrict__ tail, const int* __restrict__ negi,
    const unsigned short* __restrict__ emb, const unsigned short* __restrict__ rtab,
    const float* __restrict__ st1, const unsigned short* __restrict__ gm1,
    const unsigned short* __restrict__ bt1,
    void* __restrict__ outp, const int* __restrict__ flag)
{
    const int wave = threadIdx.x >> 6, lane = threadIdx.x & 63;
    const int w = blockIdx.x * 4 + wave;   // grid exact: (BATCH + BATCH*NNEG)/4
    const float inv_n = 1.0f / (float)N_ENTS;
    const int f0 = lane * 2, f1 = f0 + 1;
    const float mu0 = st1[f0] * inv_n, mu1 = st1[f1] * inv_n;
    const float va0 = st1[DIM + f0] * inv_n - mu0 * mu0;
    const float va1 = st1[DIM + f1] * inv_n - mu1 * mu1;
    const float g0 = bf2f(gm1[f0]) * rsqrtf(va0 + BN_EPS);
    const float g1 = bf2f(gm1[f1]) * rsqrtf(va1 + BN_EPS);
    const float o0 = bf2f(bt1[f0]) - mu0 * g0;
    const float o1 = bf2f(bt1[f1]) - mu1 * g1;

    int i, t;
    if (w < BATCH) { i = w; t = tail[w]; }
    else { const int w2 = w - BATCH; i = w2 >> 6; t = negi[w2]; }
    const uint hv = ((const uint*)emb)[(size_t)head[i] * 64 + lane];
    const uint rv = ((const uint*)rtab)[(size_t)rel[i] * 64 + lane];
    const uint tv = ((const uint*)emb)[(size_t)t * 64 + lane];
    const float h0 = fmaxf(fmaf(bflo(hv), g0, o0), 0.f);
    const float h1 = fmaxf(fmaf(bfhi(hv), g1, o1), 0.f);
    const float t0 = fmaxf(fmaf(bflo(tv), g0, o0), 0.f);
    const float t1 = fmaxf(fmaf(bfhi(tv), g1, o1), 0.f);
    const float d0 = (h0 + bflo(rv)) - t0;
    const float d1 = (h1 + bfhi(rv)) - t1;
    float s = d0 * d0 + d1 * d1;
#pragma unroll
    for (int m = 32; m >= 1; m >>= 1) s += __shfl_xor(s, m, 64);
    if (lane == 0) {
        const float v = -sqrtf(s);
        if (flag[0]) ((unsigned short*)outp)[w] = f2bf(v);
        else         ((float*)outp)[w] = v;
    }
}

extern "C" void kernel_launch(void* const* d_in, const int* in_sizes, int n_in,
                              void* d_out, int out_size, void* d_ws, size_t ws_size,
                              hipStream_t stream)
{
    const int* head = (const int*)d_in[0];
    const int* rel  = (const int*)d_in[1];
    const int* tail = (const int*)d_in[2];
    const int* negi = (const int*)d_in[3];
    const int* eidx = (const int*)d_in[4];
    const int* etyp = (const int*)d_in[5];
    const void* ent_tab = d_in[6];
    const void* rtab_in = d_in[7];
    const void* bases_in = d_in[8];
    const void* coeffs_in = d_in[9];
    const void* wsl_in = d_in[10];
    const void* bsl_in = d_in[11];
    const void* gamma_in = d_in[12];
    const void* beta_in = d_in[13];

    char* ws = (char*)d_ws;
    size_t off = 0;
    auto alloc = [&](size_t bytes) -> char* {
        char* p = ws + off;
        off += (bytes + 511) & ~(size_t)511;
        return p;
    };
    int* flag            = (int*)alloc(4);
    int* cnt             = (int*)alloc((size_t)N_ENTS * 4);
    uint* bucket         = (uint*)alloc((size_t)N_ENTS * BCAP * 4);             // 25.6 MB
    unsigned short* xrow = (unsigned short*)alloc((size_t)N_ENTS * DIM * 2);    // fp32-input path only
    unsigned short* outA = (unsigned short*)alloc((size_t)N_ENTS * DIM * 2);    // layer-0 raw out
    unsigned short* outB = (unsigned short*)alloc((size_t)N_ENTS * DIM * 2);    // layer-1 raw out
    unsigned short* par  = (unsigned short*)alloc((size_t)P_TOTAL * 2);
    unsigned short* WtT  = (unsigned short*)alloc((size_t)2 * 81920 * 2);
    float* cf32          = (float*)alloc((size_t)2 * 17 * 4 * 4);
    float* pstats        = (float*)alloc((size_t)NBLK2 * 256 * 4);              // 3.2 MB
    float* stats         = (float*)alloc(2 * 2 * DIM * 4);
    (void)ws_size; (void)in_sizes; (void)n_in; (void)out_size;

    const int* esrc = eidx;
    const int* edst = eidx + NEDGE;

    // 8 dispatches total (was 11): detect(+stats zero), conv(+WtT+cf32+cnt zero+params),
    // fillB, fused0, stats0, fused1, stats1, score.
    k_detect<<<1, 256, 0, stream>>>((const unsigned int*)ent_tab, flag, stats);

    k_conv<<<B_GRID, 256, 0, stream>>>(
        ent_tab, xrow, rtab_in, bases_in, coeffs_in, wsl_in, bsl_in, gamma_in, beta_in,
        par, WtT, cf32, cnt, flag);

    k_fillB<<<NEDGE / 256, 256, 0, stream>>>(esrc, edst, etyp, cnt, bucket);

    // layer 0 (no BN on input)
    k_fused<<<NBLK2, 256, 0, stream>>>(
        bucket, cnt, cf32, xrow, ent_tab, flag, 0,
        stats, par + P_GAMMA, par + P_BETA,          // unused at lay 0
        WtT, par + P_BSL, outA, pstats);
    k_stats<<<125, 256, 0, stream>>>(pstats, stats);

    // layer 1 (BN0+ReLU fused on the fly)
    k_fused<<<NBLK2, 256, 0, stream>>>(
        bucket, cnt, cf32 + 68, outA, ent_tab, flag, 1,
        stats, par + P_GAMMA, par + P_BETA,
        WtT + 81920, par + P_BSL + DIM, outB, pstats);
    k_stats<<<125, 256, 0, stream>>>(pstats, stats + 2 * DIM);

    k_score<<<(BATCH + BATCH * NNEG) / 4, 256, 0, stream>>>(
        head, rel, tail, negi, outB, par + P_REL,
        stats + 2 * DIM, par + P_GAMMA + DIM, par + P_BETA + DIM,
        d_out, flag);
}

// Round 10
// 341.626 us; speedup vs baseline: 1.1954x; 1.0629x over previous
//
#include <hip/hip_runtime.h>
#include <stdint.h>

// Problem constants
#define N_ENTS  100000
#define N_RELS  16
#define DIM     128
#define NB      4
#define TILE_U  10240           // ushorts per WtT n-tile: 80*16*8
#define NEDGE   640000
#define BATCH   1024
#define NNEG    64
#define BN_EPS  1e-5f
#define BCAP    64              // bucket capacity per node
#define SENTR   0x01000000u     // sentinel record: rel=16 (zero coeff), src=0
#define NPB     32              // nodes per fused block
#define NBLK2   3125            // N_ENTS/NPB exact

// merged k_conv block ranges
#define B_X     0               // [0,6250): x fp32->bf16 (early-exit if bf16)
#define B_CNT   6250            // [6250,6348): zero cnt (98 blocks of uint4)
#define B_TW    6348            // [6348,6428): WtT build from RAW inputs (80 blocks)
#define B_CF    6428            // cf32 table (1 block)
#define B_PAR   6429            // [6429,6440): small param convert (2816 elems)
#define B_GRID  6440

// converted-parameter buffer layout (ushort offsets) — only small params now
#define P_REL    0        // [16][128]
#define P_BSL    2048     // [2][128]
#define P_GAMMA  2304     // [2][128]
#define P_BETA   2560     // [2][128]
#define P_TOTAL  2816

typedef unsigned int uint;
typedef short short8 __attribute__((ext_vector_type(8)));
typedef float f4 __attribute__((ext_vector_type(4)));

__device__ __forceinline__ float bf2f(unsigned short u) {
    return __uint_as_float(((unsigned int)u) << 16);
}
__device__ __forceinline__ float bflo(unsigned int u) { return __uint_as_float(u << 16); }
__device__ __forceinline__ float bfhi(unsigned int u) { return __uint_as_float(u & 0xffff0000u); }
__device__ __forceinline__ unsigned short f2bf(float f) {
    unsigned int x = __float_as_uint(f);
    x += 0x7fffu + ((x >> 16) & 1u);
    return (unsigned short)(x >> 16);
}
__device__ __forceinline__ unsigned int pack2(float a, float b) {
    return (unsigned int)f2bf(a) | ((unsigned int)f2bf(b) << 16);
}

// ---------------- dtype detection (fp32 vs bf16 storage) + stats zero ----------------
__device__ __forceinline__ int bf16_like(unsigned int h) {
    unsigned int m = h & 0x7FFFu;
    return (m == 0u) || (m >= 0x2D00u && m < 0x4400u);
}
__global__ __launch_bounds__(256) void k_detect(const unsigned int* __restrict__ ent,
                                                int* __restrict__ flag,
                                                float* __restrict__ stats) {
    __shared__ int cnt[256];
    unsigned int u = ent[threadIdx.x];
    cnt[threadIdx.x] = bf16_like(u & 0xFFFFu) & bf16_like(u >> 16);
    stats[threadIdx.x] = 0.f;                      // zero stats[512] inline
    stats[256 + threadIdx.x] = 0.f;
    __syncthreads();
    for (int s = 128; s > 0; s >>= 1) {
        if (threadIdx.x < s) cnt[threadIdx.x] += cnt[threadIdx.x + s];
        __syncthreads();
    }
    if (threadIdx.x == 0) flag[0] = (cnt[0] >= 140) ? 1 : 0;
}

// ---------------- merged convert/setup kernel ----------------
// x convert (fp32 path), cnt zero, WtT build (from raw inputs), cf32, small params.
__device__ __forceinline__ unsigned short cvt1(const void* src, int i, int isbf) {
    return isbf ? ((const unsigned short*)src)[i] : f2bf(((const float*)src)[i]);
}
__global__ __launch_bounds__(256) void k_conv(
    const void* __restrict__ src, unsigned short* __restrict__ xrow,
    const void* __restrict__ rtab, const void* __restrict__ bases,
    const void* __restrict__ coeffs, const void* __restrict__ wsl,
    const void* __restrict__ bsl, const void* __restrict__ gamma,
    const void* __restrict__ beta,
    unsigned short* __restrict__ par, unsigned short* __restrict__ WtT,
    float* __restrict__ cf32, int* __restrict__ cnt, const int* __restrict__ flag)
{
    const int b = blockIdx.x;
    const int isbf = flag[0];
    if (b < B_CNT) {                               // ---- x conversion
        if (isbf) return;                          // bf16 input: ent used directly
        const int kc = threadIdx.x >> 4, r = threadIdx.x & 15;
        const int n = b * 16 + r;
        const size_t e0 = (size_t)n * DIM + kc * 8;
        const float4 f0 = *(const float4*)((const float*)src + e0);
        const float4 f1 = *(const float4*)((const float*)src + e0 + 4);
        uint4 w;
        w.x = pack2(f0.x, f0.y); w.y = pack2(f0.z, f0.w);
        w.z = pack2(f1.x, f1.y); w.w = pack2(f1.z, f1.w);
        *(uint4*)(xrow + e0) = w;
        return;
    }
    if (b < B_TW) {                                // ---- zero cnt via uint4 stores
        const int i = (b - B_CNT) * 256 + threadIdx.x;   // uint4 index
        if (i < N_ENTS / 4) {
            uint4 z = {0, 0, 0, 0};
            ((uint4*)cnt)[i] = z;
        }
        return;
    }
    if (b < B_CF) {                                // ---- WtT from RAW wsl/bases
        const int i = (b - B_TW) * 256 + threadIdx.x;    // [0, 20480)
        const int l = i / 10240;
        const int rem = i - l * 10240;
        const int jt2 = rem / 1280;
        const int rem2 = rem - jt2 * 1280;
        const int kc = rem2 >> 4, r = rem2 & 15;
        const int n = jt2 * 16 + r;
        unsigned short v[8];
#pragma unroll
        for (int e = 0; e < 8; ++e) {
            const int k = kc * 8 + e;
            v[e] = (k < DIM)
                ? cvt1(wsl,   l * DIM * DIM + k * DIM + n, isbf)
                : cvt1(bases, l * NB * DIM * DIM + (k - DIM) * DIM + n, isbf);
        }
        *(uint4*)(WtT + (size_t)l * 81920 + (size_t)jt2 * TILE_U + (size_t)kc * 128 + r * 8) = *(uint4*)v;
        return;
    }
    if (b == B_CF) {                               // ---- cf32 [2][17][4], rel=16 -> 0
        const int i = threadIdx.x;
        if (i < 2 * 17 * 4) {
            const int l = i / 68, rem = i - l * 68, r = rem >> 2, bb = rem & 3;
            const int idx = l * N_RELS * NB + r * NB + bb;
            cf32[i] = (r < N_RELS)
                ? (isbf ? bf2f(((const unsigned short*)coeffs)[idx])
                        : ((const float*)coeffs)[idx])
                : 0.f;
        }
        return;
    }
    // ---- small params: rel, bsl, gamma, beta
    const int i = (b - B_PAR) * 256 + threadIdx.x;
    if (i >= P_TOTAL) return;
    unsigned short v;
    if      (i < P_BSL)    v = cvt1(rtab,  i - P_REL,   isbf);
    else if (i < P_GAMMA)  v = cvt1(bsl,   i - P_BSL,   isbf);
    else if (i < P_BETA)   v = cvt1(gamma, i - P_GAMMA, isbf);
    else                   v = cvt1(beta,  i - P_BETA,  isbf);
    par[i] = v;
}

// ---------------- one-kernel bucket CSR: cnt + bucket[n][64] ----------------
__global__ __launch_bounds__(256) void k_fillB(const int* __restrict__ src, const int* __restrict__ dst,
                                               const int* __restrict__ et, int* __restrict__ cnt,
                                               uint* __restrict__ bucket) {
    const int e = blockIdx.x * 256 + threadIdx.x;   // grid exact: NEDGE/256
    const int d = dst[e];
    const int p = atomicAdd(&cnt[d], 1);
    if (p < BCAP) bucket[(size_t)d * BCAP + p] = (uint)src[e] | ((uint)et[e] << 20);
}

// ---------------- FUSED (BN of prev layer) + aggregate + GEMM + epilogue ----------------
// r6-proven geometry: 256 thr (4 waves), NPB=32, runtime lay, pstats epilogue.
// NEW (r10): bucket records (first 16/node), cnt, and coeffs staged in LDS by each wave
// for ITS OWN nodes (no barrier needed) — removes the ~700cy global bucket-load stall
// from the per-pr serial chain. Gathers use VGPR-offset addressing (r0 k_agg mode).
// DO NOT: min-waves 8 (r3 spill), 4-chain interleave (r7 VGPR100+qm-max4), atomic
// stats (r8 TCC contention). All measured regressions.
__global__ __launch_bounds__(256, 4) void k_fused(
    const uint* __restrict__ bucket, const int* __restrict__ cnt,
    const float* __restrict__ cf, const unsigned short* __restrict__ xin,
    const void* __restrict__ ent, const int* __restrict__ flag, const int lay,
    const float* __restrict__ stp, const unsigned short* __restrict__ gprev,
    const unsigned short* __restrict__ bprev,
    const unsigned short* __restrict__ wtT, const unsigned short* __restrict__ bsl,
    unsigned short* __restrict__ out, float* __restrict__ pstats)
{
    __shared__ unsigned short Ash[NPB * 640];            // 40960 B
    __shared__ __align__(16) uint  bkL[NPB][16];         // 2048 B: first 16 records/node
    __shared__ __align__(16) float cfL[17][4];           // 272 B coeff table
    __shared__ int cntL[NPB];                            // 128 B raw degrees
    const int tid = threadIdx.x;
    const int wave = tid >> 6, lane = tid & 63;
    const int n0 = blockIdx.x * NPB;
    const float inv_n = 1.0f / (float)N_ENTS;

    const unsigned short* __restrict__ xs =
        (lay == 0 && flag[0]) ? (const unsigned short*)ent : xin;
    const int mybase = n0 + wave * 8;

    // ---- phase 0: per-wave LDS staging of bucket records / cnt / coeffs
    {
        const int nd = wave * 8 + (lane >> 3);           // this wave's nodes only
        const int p  = lane & 7;                         // record pair 0..7 (recs 0..15)
        const uint2 rv = *(const uint2*)(bucket + (size_t)(n0 + nd) * BCAP + p * 2);
        *(uint2*)&bkL[nd][p * 2] = rv;
        if (lane < 17) {
            const float4 c4 = *(const float4*)(cf + lane * 4);
            *(float4*)&cfL[lane][0] = c4;
        }
        if (lane < 8) cntL[wave * 8 + lane] = cnt[mybase + lane];   // RAW (deg semantics)
    }

    // per-lane BN coeffs for gather columns {2*lane, 2*lane+1} (identity for lay 0)
    float gnA = 1.f, ofA = 0.f, gnB = 1.f, ofB = 0.f;
    if (lay) {
        const int f0 = lane * 2, f1 = f0 + 1;
        const float mu0 = stp[f0] * inv_n, mu1 = stp[f1] * inv_n;
        const float va0 = stp[DIM + f0] * inv_n - mu0 * mu0;
        const float va1 = stp[DIM + f1] * inv_n - mu1 * mu1;
        gnA = bf2f(gprev[f0]) * rsqrtf(va0 + BN_EPS); ofA = bf2f(bprev[f0]) - mu0 * gnA;
        gnB = bf2f(gprev[f1]) * rsqrtf(va1 + BN_EPS); ofB = bf2f(bprev[f1]) - mu1 * gnB;
    }

    // ---- phase 1: stage self rows into LDS (k 0..127 = 256B/row), swizzled, BN-applied
    {
        const int r = tid >> 3, c = tid & 7;       // 32 rows; chunks c and c+8 (16B each)
        const size_t e0 = (size_t)(n0 + r) * DIM + c * 8;
        uint4 v0 = *(const uint4*)(xs + e0);
        uint4 v1 = *(const uint4*)(xs + e0 + 64);
        if (lay) {
            uint vv[8] = {v0.x, v0.y, v0.z, v0.w, v1.x, v1.y, v1.z, v1.w};
#pragma unroll
            for (int p = 0; p < 8; ++p) {
                const int f0 = c * 8 + (p >> 2) * 64 + (p & 3) * 2;
                const float mu0 = stp[f0] * inv_n, mu1 = stp[f0 + 1] * inv_n;
                const float va0 = stp[DIM + f0] * inv_n - mu0 * mu0;
                const float va1 = stp[DIM + f0 + 1] * inv_n - mu1 * mu1;
                const float g0 = bf2f(gprev[f0]) * rsqrtf(va0 + BN_EPS);
                const float g1 = bf2f(gprev[f0 + 1]) * rsqrtf(va1 + BN_EPS);
                const float o0 = bf2f(bprev[f0]) - mu0 * g0;
                const float o1 = bf2f(bprev[f0 + 1]) - mu1 * g1;
                const float w0 = fmaxf(fmaf(bflo(vv[p]), g0, o0), 0.f);
                const float w1 = fmaxf(fmaf(bfhi(vv[p]), g1, o1), 0.f);
                vv[p] = pack2(w0, w1);
            }
            v0.x = vv[0]; v0.y = vv[1]; v0.z = vv[2]; v0.w = vv[3];
            v1.x = vv[4]; v1.y = vv[5]; v1.z = vv[6]; v1.w = vv[7];
        }
        const int byte0 = (r * 1280 + c * 16) ^ ((r & 7) << 4);
        *(uint4*)((char*)Ash + byte0) = v0;
        *(uint4*)((char*)Ash + byte0 + 128) = v1;   // +128: bit7 only, outside XOR bits 4-6
    }

    // ---- phase 2: gather-aggregate; records from LDS (broadcast), 2-node interleave
    const uint* __restrict__ x32 = (const uint*)xs;
    for (int pr = 0; pr < 4; ++pr) {
        const int la = wave * 8 + pr * 2;
        const int na = mybase + pr * 2;
        int ca = cntL[la];     if (ca > BCAP) ca = BCAP;
        int cb = cntL[la + 1]; if (cb > BCAP) cb = BCAP;
        const int qm = ((ca > cb ? ca : cb) + 7) >> 3;
        float aLo[2][NB] = {{0.f,0.f,0.f,0.f},{0.f,0.f,0.f,0.f}};
        float aHi[2][NB] = {{0.f,0.f,0.f,0.f},{0.f,0.f,0.f,0.f}};
        const uint4* __restrict__ bkg = (const uint4*)(bucket + (size_t)na * BCAP);
        for (int j = 0; j < qm; ++j) {
            uint rec[2][8];
            uint xw[2][8];
            const int b8 = j * 8;
#pragma unroll
            for (int h = 0; h < 2; ++h) {
                const int cn = h ? cb : ca;
                if (b8 < cn) {
                    if (j < 2) {                         // records 0..15: LDS broadcast
#pragma unroll
                        for (int s = 0; s < 8; ++s) rec[h][s] = bkL[la + h][b8 + s];
                    } else {                             // rare: records 16+ from global
                        const uint4 r0 = bkg[h * 16 + j * 2];
                        const uint4 r1 = bkg[h * 16 + j * 2 + 1];
                        rec[h][0] = r0.x; rec[h][1] = r0.y; rec[h][2] = r0.z; rec[h][3] = r0.w;
                        rec[h][4] = r1.x; rec[h][5] = r1.y; rec[h][6] = r1.z; rec[h][7] = r1.w;
                    }
#pragma unroll
                    for (int s = 0; s < 8; ++s) {
                        uint rr = rec[h][s];
                        if (b8 + s >= cn) rr = SENTR;    // tail mask: rel=16, src=0
                        rec[h][s] = rr;
                        xw[h][s] = x32[(size_t)(rr & 0xFFFFFu) * 64 + lane];
                    }
                }
            }
#pragma unroll
            for (int h = 0; h < 2; ++h) {
                const int cn = h ? cb : ca;
                if (b8 < cn) {
#pragma unroll
                    for (int s = 0; s < 8; ++s) {
                        const int rel = (int)(rec[h][s] >> 20);   // 16 -> zero coeffs
                        const float4 cc = *(const float4*)&cfL[rel][0];  // LDS broadcast
                        float xl, xh;
                        if (lay) {
                            xl = fmaxf(fmaf(bflo(xw[h][s]), gnA, ofA), 0.f);
                            xh = fmaxf(fmaf(bfhi(xw[h][s]), gnB, ofB), 0.f);
                        } else {
                            xl = bflo(xw[h][s]);
                            xh = bfhi(xw[h][s]);
                        }
                        aLo[h][0] = fmaf(cc.x, xl, aLo[h][0]);
                        aHi[h][0] = fmaf(cc.x, xh, aHi[h][0]);
                        aLo[h][1] = fmaf(cc.y, xl, aLo[h][1]);
                        aHi[h][1] = fmaf(cc.y, xh, aHi[h][1]);
                        aLo[h][2] = fmaf(cc.z, xl, aLo[h][2]);
                        aHi[h][2] = fmaf(cc.z, xh, aHi[h][2]);
                        aLo[h][3] = fmaf(cc.w, xl, aLo[h][3]);
                        aHi[h][3] = fmaf(cc.w, xh, aHi[h][3]);
                    }
                }
            }
        }
#pragma unroll
        for (int h = 0; h < 2; ++h) {
            const int ra = wave * 8 + pr * 2 + h;
            const int swz = (ra & 7) << 4;
#pragma unroll
            for (int b = 0; b < NB; ++b) {
                // A[ra][128 + b*128 + 2*lane .. +1]  (bank-conflict-free: lane*4 stride)
                const int byte = (ra * 1280 + 256 + b * 256 + lane * 4) ^ swz;
                *(uint*)((char*)Ash + byte) = pack2(aLo[h][b], aHi[h][b]);
            }
        }
    }

    // ---- phase 3: MFMA. wave w: m-tiles {0,1} x n-tiles {2w,2w+1}, K=640 (20 steps)
    const int quad = lane >> 4, l16 = lane & 15;
    f4 acc[2][2];
#pragma unroll
    for (int i = 0; i < 2; ++i)
#pragma unroll
        for (int j = 0; j < 2; ++j)
#pragma unroll
            for (int r = 0; r < 4; ++r) acc[i][j][r] = 0.f;

    const unsigned short* __restrict__ pB0 = wtT + (size_t)(2 * wave) * TILE_U + quad * 128 + l16 * 8;
    const unsigned short* __restrict__ pB1 = pB0 + TILE_U;
    const char* Ab = (const char*)Ash;
    const int swz = (l16 & 7) << 4;
    // even/odd ks bases: XOR touches bits 4-6 and ks*64 carries bit 6 -> two bases
    const int b0e = (l16 * 1280 + quad * 16) ^ swz;
    const int b0o = (l16 * 1280 + 64 + quad * 16) ^ swz;
    const int b1e = ((l16 + 16) * 1280 + quad * 16) ^ swz;
    const int b1o = ((l16 + 16) * 1280 + 64 + quad * 16) ^ swz;

    short8 xa0, xa1, xb0, xb1, ya0, ya1, yb0, yb1;
#define FLDA(P, s) \
    P##a0 = *(const short8*)(Ab + (((s) & 1) ? b0o : b0e) + ((s) >> 1) * 128); \
    P##a1 = *(const short8*)(Ab + (((s) & 1) ? b1o : b1e) + ((s) >> 1) * 128);
#define FLDB(P, s) \
    P##b0 = *(const short8*)(pB0 + (s) * 512); \
    P##b1 = *(const short8*)(pB1 + (s) * 512);
#define FLD(P, s) FLDA(P, s) FLDB(P, s)
#define FMM(P) \
    acc[0][0] = __builtin_amdgcn_mfma_f32_16x16x32_bf16(P##a0, P##b0, acc[0][0], 0, 0, 0); \
    acc[0][1] = __builtin_amdgcn_mfma_f32_16x16x32_bf16(P##a0, P##b1, acc[0][1], 0, 0, 0); \
    acc[1][0] = __builtin_amdgcn_mfma_f32_16x16x32_bf16(P##a1, P##b0, acc[1][0], 0, 0, 0); \
    acc[1][1] = __builtin_amdgcn_mfma_f32_16x16x32_bf16(P##a1, P##b1, acc[1][1], 0, 0, 0);

    // B loads are global (no LDS dependency): issue before the barrier
    FLDB(x, 0) FLDB(y, 1)
    __syncthreads();
    FLDA(x, 0) FLDA(y, 1)
    FMM(x) FLD(x, 2)
    FMM(y) FLD(y, 3)
    FMM(x) FLD(x, 4)
    FMM(y) FLD(y, 5)
    FMM(x) FLD(x, 6)
    FMM(y) FLD(y, 7)
    FMM(x) FLD(x, 8)
    FMM(y) FLD(y, 9)
    FMM(x) FLD(x, 10)
    FMM(y) FLD(y, 11)
    FMM(x) FLD(x, 12)
    FMM(y) FLD(y, 13)
    FMM(x) FLD(x, 14)
    FMM(y) FLD(y, 15)
    FMM(x) FLD(x, 16)
    FMM(y) FLD(y, 17)
    FMM(x) FLD(x, 18)
    FMM(y) FLD(y, 19)
    FMM(x)
    FMM(y)
#undef FLDA
#undef FLDB
#undef FLD
#undef FMM

    // ---- epilogue: o = (acc + bias)/deg, bf16 store, per-block BN partial stats
    // cntL valid across waves here: phase-3 __syncthreads() ordered phase-0 writes.
    float ssum[2] = {0.f, 0.f}, sssq[2] = {0.f, 0.f};
#pragma unroll
    for (int m = 0; m < 2; ++m) {
#pragma unroll
        for (int r = 0; r < 4; ++r) {
            const int lrow = m * 16 + quad * 4 + r;
            const int row = n0 + lrow;                 // always < N_ENTS (3125*32 exact)
            const float rdeg = 1.0f / fmaxf((float)cntL[lrow], 1.0f);
#pragma unroll
            for (int n = 0; n < 2; ++n) {
                const int col = (2 * wave + n) * 16 + l16;
                const float o = (acc[m][n][r] + bf2f(bsl[col])) * rdeg;
                out[(size_t)row * DIM + col] = f2bf(o);
                ssum[n] += o;
                sssq[n] += o * o;
            }
        }
    }
#pragma unroll
    for (int n = 0; n < 2; ++n) {
        float s = ssum[n], q2 = sssq[n];
        s += __shfl_xor(s, 16, 64);  s += __shfl_xor(s, 32, 64);
        q2 += __shfl_xor(q2, 16, 64); q2 += __shfl_xor(q2, 32, 64);
        if (quad == 0) {
            const int col = (2 * wave + n) * 16 + l16;
            pstats[(size_t)blockIdx.x * 256 + col] = s;
            pstats[(size_t)blockIdx.x * 256 + 128 + col] = q2;
        }
    }
}

// ---------------- reduce per-block stats -> st[256] ----------------
__global__ __launch_bounds__(256) void k_stats(const float* __restrict__ pstats,
                                               float* __restrict__ st) {
    const int o = threadIdx.x;
    const int b0 = blockIdx.x * 25;                // grid 125: 125*25 = 3125 exact
    float s = 0.f;
    for (int b = b0; b < b0 + 25; ++b)
        s += pstats[(size_t)b * 256 + o];
    atomicAdd(&st[o], s);
}

// ---------------- fused scoring: BN1+ReLU applied to gathered embeddings ----------------
__global__ __launch_bounds__(256) void k_score(
    const int* __restrict__ head, const int* __restrict__ rel,
    const int* __restrict__ tail, const int* __restrict__ negi,
    const unsigned short* __restrict__ emb, const unsigned short* __restrict__ rtab,
    const float* __restrict__ st1, const unsigned short* __restrict__ gm1,
    const unsigned short* __restrict__ bt1,
    void* __restrict__ outp, const int* __restrict__ flag)
{
    const int wave = threadIdx.x >> 6, lane = threadIdx.x & 63;
    const int w = blockIdx.x * 4 + wave;   // grid exact: (BATCH + BATCH*NNEG)/4
    const float inv_n = 1.0f / (float)N_ENTS;
    const int f0 = lane * 2, f1 = f0 + 1;
    const float mu0 = st1[f0] * inv_n, mu1 = st1[f1] * inv_n;
    const float va0 = st1[DIM + f0] * inv_n - mu0 * mu0;
    const float va1 = st1[DIM + f1] * inv_n - mu1 * mu1;
    const float g0 = bf2f(gm1[f0]) * rsqrtf(va0 + BN_EPS);
    const float g1 = bf2f(gm1[f1]) * rsqrtf(va1 + BN_EPS);
    const float o0 = bf2f(bt1[f0]) - mu0 * g0;
    const float o1 = bf2f(bt1[f1]) - mu1 * g1;

    int i, t;
    if (w < BATCH) { i = w; t = tail[w]; }
    else { const int w2 = w - BATCH; i = w2 >> 6; t = negi[w2]; }
    const uint hv = ((const uint*)emb)[(size_t)head[i] * 64 + lane];
    const uint rv = ((const uint*)rtab)[(size_t)rel[i] * 64 + lane];
    const uint tv = ((const uint*)emb)[(size_t)t * 64 + lane];
    const float h0 = fmaxf(fmaf(bflo(hv), g0, o0), 0.f);
    const float h1 = fmaxf(fmaf(bfhi(hv), g1, o1), 0.f);
    const float t0 = fmaxf(fmaf(bflo(tv), g0, o0), 0.f);
    const float t1 = fmaxf(fmaf(bfhi(tv), g1, o1), 0.f);
    const float d0 = (h0 + bflo(rv)) - t0;
    const float d1 = (h1 + bfhi(rv)) - t1;
    float s = d0 * d0 + d1 * d1;
#pragma unroll
    for (int m = 32; m >= 1; m >>= 1) s += __shfl_xor(s, m, 64);
    if (lane == 0) {
        const float v = -sqrtf(s);
        if (flag[0]) ((unsigned short*)outp)[w] = f2bf(v);
        else         ((float*)outp)[w] = v;
    }
}

extern "C" void kernel_launch(void* const* d_in, const int* in_sizes, int n_in,
                              void* d_out, int out_size, void* d_ws, size_t ws_size,
                              hipStream_t stream)
{
    const int* head = (const int*)d_in[0];
    const int* rel  = (const int*)d_in[1];
    const int* tail = (const int*)d_in[2];
    const int* negi = (const int*)d_in[3];
    const int* eidx = (const int*)d_in[4];
    const int* etyp = (const int*)d_in[5];
    const void* ent_tab = d_in[6];
    const void* rtab_in = d_in[7];
    const void* bases_in = d_in[8];
    const void* coeffs_in = d_in[9];
    const void* wsl_in = d_in[10];
    const void* bsl_in = d_in[11];
    const void* gamma_in = d_in[12];
    const void* beta_in = d_in[13];

    char* ws = (char*)d_ws;
    size_t off = 0;
    auto alloc = [&](size_t bytes) -> char* {
        char* p = ws + off;
        off += (bytes + 511) & ~(size_t)511;
        return p;
    };
    int* flag            = (int*)alloc(4);
    int* cnt             = (int*)alloc((size_t)N_ENTS * 4);
    uint* bucket         = (uint*)alloc((size_t)N_ENTS * BCAP * 4);             // 25.6 MB
    unsigned short* xrow = (unsigned short*)alloc((size_t)N_ENTS * DIM * 2);    // fp32-input path only
    unsigned short* outA = (unsigned short*)alloc((size_t)N_ENTS * DIM * 2);    // layer-0 raw out
    unsigned short* outB = (unsigned short*)alloc((size_t)N_ENTS * DIM * 2);    // layer-1 raw out
    unsigned short* par  = (unsigned short*)alloc((size_t)P_TOTAL * 2);
    unsigned short* WtT  = (unsigned short*)alloc((size_t)2 * 81920 * 2);
    float* cf32          = (float*)alloc((size_t)2 * 17 * 4 * 4);
    float* pstats        = (float*)alloc((size_t)NBLK2 * 256 * 4);              // 3.2 MB
    float* stats         = (float*)alloc(2 * 2 * DIM * 4);
    (void)ws_size; (void)in_sizes; (void)n_in; (void)out_size;

    const int* esrc = eidx;
    const int* edst = eidx + NEDGE;

    // 8 dispatches: detect(+stats zero), conv(+WtT+cf32+cnt zero+params),
    // fillB, fused0, stats0, fused1, stats1, score.
    k_detect<<<1, 256, 0, stream>>>((const unsigned int*)ent_tab, flag, stats);

    k_conv<<<B_GRID, 256, 0, stream>>>(
        ent_tab, xrow, rtab_in, bases_in, coeffs_in, wsl_in, bsl_in, gamma_in, beta_in,
        par, WtT, cf32, cnt, flag);

    k_fillB<<<NEDGE / 256, 256, 0, stream>>>(esrc, edst, etyp, cnt, bucket);

    // layer 0 (no BN on input)
    k_fused<<<NBLK2, 256, 0, stream>>>(
        bucket, cnt, cf32, xrow, ent_tab, flag, 0,
        stats, par + P_GAMMA, par + P_BETA,          // unused at lay 0
        WtT, par + P_BSL, outA, pstats);
    k_stats<<<125, 256, 0, stream>>>(pstats, stats);

    // layer 1 (BN0+ReLU fused on the fly)
    k_fused<<<NBLK2, 256, 0, stream>>>(
        bucket, cnt, cf32 + 68, outA, ent_tab, flag, 1,
        stats, par + P_GAMMA, par + P_BETA,
        WtT + 81920, par + P_BSL + DIM, outB, pstats);
    k_stats<<<125, 256, 0, stream>>>(pstats, stats + 2 * DIM);

    k_score<<<(BATCH + BATCH * NNEG) / 4, 256, 0, stream>>>(
        head, rel, tail, negi, outB, par + P_REL,
        stats + 2 * DIM, par + P_GAMMA + DIM, par + P_BETA + DIM,
        d_out, flag);
}